// Round 12
// baseline (650.954 us; speedup 1.0000x reference)
//
#include <hip/hip_runtime.h>
#include <hip/hip_bf16.h>
#include <cstdint>
#include <cstddef>

// ---------------------------------------------------------------------------
// ImprovedCrossScaleGNN on MI355X (gfx950).
// Inputs float32 + int32, output float32. bf16 MFMA GEMMs, f32 stats.
// R11->R12: XCD-SLICED gather. m (12.8 MB) > 4 MB per-XCD L2 -> edge row
// reads were L3-bound. Each block now handles a 32-feature slice (one 64B
// line per edge-row read), slice = (blockIdx&7)>>1 so each XCD's working
// set is 3.2 MB -> L2-resident. cs/cw via nontemporal loads, agg via
// nontemporal stores (keep L2 for m). Summation order unchanged.
// ---------------------------------------------------------------------------

typedef __attribute__((ext_vector_type(8))) short bf16x8;
typedef __attribute__((ext_vector_type(4))) float f32x4;

#define EPSV 1e-5f

__device__ __forceinline__ float b2f(unsigned short u) {
    union { unsigned int i; float f; } x; x.i = ((unsigned int)u) << 16; return x.f;
}
__device__ __forceinline__ unsigned short f2b(float f) {
    union { float f; unsigned int i; } x; x.f = f;
    unsigned int i = x.i;
    return (unsigned short)((i + 0x7fffu + ((i >> 16) & 1u)) >> 16);
}

// ---------------- prep: weights -> fragment-linear bf16 + feature casts ------
__global__ void prep_kernel(const float* __restrict__ node_W, const float* __restrict__ comm_W,
                            const float* __restrict__ cls_W1, const float* __restrict__ attn_in_w,
                            const float* __restrict__ attn_out_w, const float* __restrict__ comm_feat,
                            const float* __restrict__ node_feat,
                            unsigned short* __restrict__ WtN, unsigned short* __restrict__ WtC,
                            unsigned short* __restrict__ W1t, unsigned short* __restrict__ WinB,
                            unsigned short* __restrict__ WoutB, unsigned short* __restrict__ cfb,
                            unsigned short* __restrict__ nfb, int nC128, int nN128) {
    int idx = blockIdx.x * 256 + threadIdx.x;
    if (idx < 49152) {
        int l = idx >> 14, e = idx & 16383;
        int j = e & 7, lane = (e >> 3) & 63, kc = (e >> 9) & 3, t = e >> 11;
        int col = t * 16 + (lane & 15);
        int k = (lane >> 4) * 8 + kc * 32 + j;
        WtN[idx] = f2b(node_W[l * 16384 + k * 128 + col]); return;
    }
    idx -= 49152;
    if (idx < 49152) {
        int l = idx >> 14, e = idx & 16383;
        int j = e & 7, lane = (e >> 3) & 63, kc = (e >> 9) & 3, t = e >> 11;
        int col = t * 16 + (lane & 15);
        int k = (lane >> 4) * 8 + kc * 32 + j;
        WtC[idx] = f2b(comm_W[l * 16384 + k * 128 + col]); return;
    }
    idx -= 49152;
    if (idx < 8192) {
        int e = idx;
        int j = e & 7, lane = (e >> 3) & 63, kc = (e >> 9) & 3, t = e >> 11;
        int col = t * 16 + (lane & 15);
        int k = (lane >> 4) * 8 + kc * 32 + j;
        W1t[idx] = f2b(cls_W1[k * 64 + col]); return;
    }
    idx -= 8192;
    if (idx < 49152) {
        int e = idx;
        int j = e & 7, lane = (e >> 3) & 63, kc = (e >> 9) & 3, t = e >> 11;
        int col = t * 16 + (lane & 15);
        int k = (lane >> 4) * 8 + kc * 32 + j;
        WinB[idx] = f2b(attn_in_w[col * 128 + k]); return;
    }
    idx -= 49152;
    if (idx < 16384) {
        int e = idx;
        int j = e & 7, lane = (e >> 3) & 63, kc = (e >> 9) & 3, t = e >> 11;
        int col = t * 16 + (lane & 15);
        int k = (lane >> 4) * 8 + kc * 32 + j;
        WoutB[idx] = f2b(attn_out_w[col * 128 + k]); return;
    }
    idx -= 16384;
    if (idx < nC128) { cfb[idx] = f2b(comm_feat[idx]); return; }
    idx -= nC128;
    if (idx < nN128) { nfb[idx] = f2b(node_feat[idx]); }
}

// ---------------- CSR build (dual) ----------------
__global__ void count_dual(const int* __restrict__ nd, int* __restrict__ cnt_n, int nE,
                           const int* __restrict__ cd, int* __restrict__ cnt_c, int cE) {
    int t = blockIdx.x * 256 + threadIdx.x;
    if (t < nE) atomicAdd(&cnt_n[nd[t]], 1);
    else if (t - nE < cE) atomicAdd(&cnt_c[cd[t - nE]], 1);
}

__global__ void dinv_dual(const int* __restrict__ cnt_n, float* __restrict__ di_n, int nN,
                          const int* __restrict__ cnt_c, float* __restrict__ di_c, int nC) {
    int t = blockIdx.x * 256 + threadIdx.x;
    if (t < nN) di_n[t] = rsqrtf((float)cnt_n[t] + 1.0f);
    else if (t - nN < nC) di_c[t - nN] = rsqrtf((float)cnt_c[t - nN] + 1.0f);
}

// scans PADDED counts: ceil8(cnt)
__global__ void scan_block_dual(const int* __restrict__ cnt_n, int* __restrict__ rs_n,
                                int* __restrict__ bsum_n, int nN, int nbN,
                                const int* __restrict__ cnt_c, int* __restrict__ rs_c,
                                int* __restrict__ bsum_c, int nC) {
    __shared__ int tmp[2048];
    const int* cnt; int* excl; int* bsum; int n, lb;
    if ((int)blockIdx.x < nbN) { cnt = cnt_n; excl = rs_n; bsum = bsum_n; n = nN; lb = blockIdx.x; }
    else { cnt = cnt_c; excl = rs_c; bsum = bsum_c; n = nC; lb = blockIdx.x - nbN; }
    int tid = threadIdx.x;
    int gid = lb * 1024 + tid;
    int v = (gid < n) ? ((cnt[gid] + 7) & ~7) : 0;
    int buf = 0;
    tmp[tid] = v;
    __syncthreads();
    for (int d = 1; d < 1024; d <<= 1) {
        int t = tmp[buf * 1024 + tid];
        int add = (tid >= d) ? tmp[buf * 1024 + tid - d] : 0;
        tmp[(1 - buf) * 1024 + tid] = t + add;
        buf = 1 - buf;
        __syncthreads();
    }
    int inc = tmp[buf * 1024 + tid];
    if (gid < n) excl[gid] = inc - v;
    if (tid == 1023) bsum[lb] = inc;
}

__global__ void scan_sums_dual(int* __restrict__ bsum_n, int nbN,
                               int* __restrict__ bsum_c, int nbC) {
    if (threadIdx.x == 0) {
        int acc = 0;
        for (int i = 0; i < nbN; ++i) { int t = bsum_n[i]; bsum_n[i] = acc; acc += t; }
    } else if (threadIdx.x == 1) {
        int acc = 0;
        for (int i = 0; i < nbC; ++i) { int t = bsum_c[i]; bsum_c[i] = acc; acc += t; }
    }
}

__global__ void scan_add_dual(int* __restrict__ rs_n, const int* __restrict__ bsum_n, int nN,
                              int* __restrict__ rs_c, const int* __restrict__ bsum_c, int nC) {
    int gid = blockIdx.x * 256 + threadIdx.x;
    if (gid < nN) rs_n[gid] += bsum_n[gid >> 10];
    else {
        int g = gid - nN;
        if (g < nC) rs_c[g] += bsum_c[g >> 10];
    }
}

__global__ void fill_dual(const int* __restrict__ ns, const int* __restrict__ ndst,
                          const float* __restrict__ di_n, const int* __restrict__ rs_n,
                          int* __restrict__ cur_n, int* __restrict__ csrc_n,
                          float* __restrict__ cw_n, int nE,
                          const int* __restrict__ cs, const int* __restrict__ cdst,
                          const float* __restrict__ di_c, const int* __restrict__ rs_c,
                          int* __restrict__ cur_c, int* __restrict__ csrc_c,
                          float* __restrict__ cw_c, int cE) {
    int e = blockIdx.x * 256 + threadIdx.x;
    if (e < nE) {
        int s = ns[e], d = ndst[e];
        int pos = atomicAdd(&cur_n[d], 1);
        int slot = rs_n[d] + pos;
        csrc_n[slot] = s;
        cw_n[slot] = di_n[s] * di_n[d];
    } else if (e - nE < cE) {
        int ee = e - nE;
        int s = cs[ee], d = cdst[ee];
        int pos = atomicAdd(&cur_c[d], 1);
        int slot = rs_c[d] + pos;
        csrc_c[slot] = s;
        cw_c[slot] = di_c[s] * di_c[d];
    }
}

// ---------------- MFMA GEMM wave body: 16 rows x 128 cols, bf16 out ----------
__device__ __forceinline__ void gemm_wave_128(const unsigned short* __restrict__ A,
                                              const unsigned short* __restrict__ Bt,
                                              unsigned short* __restrict__ D,
                                              int M, int m0, int lane) {
    int r = lane & 15, q = lane >> 4;
    int arow = m0 + r; if (arow >= M) arow = M - 1;
    const unsigned short* ap = A + (size_t)arow * 128 + q * 8;
    bf16x8 afrag[4];
#pragma unroll
    for (int kc = 0; kc < 4; ++kc)
        afrag[kc] = *(const bf16x8*)(const void*)(ap + kc * 32);
#pragma unroll
    for (int tt = 0; tt < 8; ++tt) {
        f32x4 acc = {0.f, 0.f, 0.f, 0.f};
#pragma unroll
        for (int kc = 0; kc < 4; ++kc) {
            bf16x8 bfrag = *(const bf16x8*)(const void*)(Bt + (((size_t)tt * 4 + kc) << 9) + lane * 8);
            acc = __builtin_amdgcn_mfma_f32_16x16x32_bf16(afrag[kc], bfrag, acc, 0, 0, 0);
        }
        int n0 = tt * 16;
#pragma unroll
        for (int t = 0; t < 4; ++t) {
            int row = m0 + q * 4 + t;
            if (row < M) D[(size_t)row * 128 + n0 + r] = f2b(acc[t]);
        }
    }
}

__global__ __launch_bounds__(256) void gemm_dual(
    const unsigned short* __restrict__ A0, const unsigned short* __restrict__ Bt0,
    unsigned short* __restrict__ D0, int M0, int blocksA,
    const unsigned short* __restrict__ A1, const unsigned short* __restrict__ Bt1,
    unsigned short* __restrict__ D1, int M1) {
    int blk = blockIdx.x;
    const unsigned short *A, *Bt; unsigned short* D; int M, lb;
    if (blk < blocksA) { A = A0; Bt = Bt0; D = D0; M = M0; lb = blk; }
    else { A = A1; Bt = Bt1; D = D1; M = M1; lb = blk - blocksA; }
    int m0 = (lb * 4 + (int)(threadIdx.x >> 6)) * 16;
    if (m0 >= M) return;
    gemm_wave_128(A, Bt, D, M, m0, threadIdx.x & 63);
}

// classifier GEMM (generic Ncol, f32 out, bias); Bt fragment-linear
__global__ void gemm_kernel(const unsigned short* __restrict__ A,
                            const unsigned short* __restrict__ Bt,
                            const float* __restrict__ bias,
                            float* __restrict__ D, int M, int Ncol) {
    int wave = (blockIdx.x * blockDim.x + threadIdx.x) >> 6;
    int lane = threadIdx.x & 63;
    int m0 = wave * 16;
    if (m0 >= M) return;
    int r = lane & 15, q = lane >> 4;
    int arow = m0 + r; if (arow >= M) arow = M - 1;
    const unsigned short* ap = A + (size_t)arow * 128 + q * 8;
    bf16x8 afrag[4];
#pragma unroll
    for (int kc = 0; kc < 4; ++kc)
        afrag[kc] = *(const bf16x8*)(const void*)(ap + kc * 32);
    int ntiles = Ncol >> 4;
    for (int tt = 0; tt < ntiles; ++tt) {
        f32x4 acc = {0.f, 0.f, 0.f, 0.f};
#pragma unroll
        for (int kc = 0; kc < 4; ++kc) {
            bf16x8 bfrag = *(const bf16x8*)(const void*)(Bt + (((size_t)tt * 4 + kc) << 9) + lane * 8);
            acc = __builtin_amdgcn_mfma_f32_16x16x32_bf16(afrag[kc], bfrag, acc, 0, 0, 0);
        }
        int n0 = tt * 16;
        float bv = bias[n0 + r];
#pragma unroll
        for (int t = 0; t < 4; ++t) {
            int row = m0 + q * 4 + t;
            if (row < M) D[(size_t)row * Ncol + n0 + r] = acc[t] + bv;
        }
    }
}

// ---------------- gather (CSR, XCD-sliced), dual-branch ----------------------
// Block = 16 nodes x ONE 32-feature slice. slice = (lb&7)>>1 so (by the
// round-robin block->XCD heuristic) each XCD touches only its 3.2 MB slice
// of m -> L2-resident. Each edge-row read = exactly one 64B line.
// 16 lanes per node (2 feats/lane); rows padded to x8 (8 lines in flight).
__global__ __launch_bounds__(256) void gather_dual(
    const unsigned short* __restrict__ m0, const int* __restrict__ rs0,
    const int* __restrict__ cnt0,
    const int* __restrict__ cs0, const float* __restrict__ cw0,
    const float* __restrict__ di0, const float* __restrict__ b0,
    float* __restrict__ agg0, int n0, int blocksA,
    const unsigned short* __restrict__ m1, const int* __restrict__ rs1,
    const int* __restrict__ cnt1,
    const int* __restrict__ cs1, const float* __restrict__ cw1,
    const float* __restrict__ di1, const float* __restrict__ b1,
    float* __restrict__ agg1, int n1) {
    int blk = blockIdx.x;
    const unsigned short* m; const int *rs, *cnt, *cs; const float *cw, *di, *bias;
    float *agg; int n, lb;
    if (blk < blocksA) { m = m0; rs = rs0; cnt = cnt0; cs = cs0; cw = cw0; di = di0; bias = b0; agg = agg0; n = n0; lb = blk; }
    else { m = m1; rs = rs1; cnt = cnt1; cs = cs1; cw = cw1; di = di1; bias = b1; agg = agg1; n = n1; lb = blk - blocksA; }
    int xcd = lb & 7;
    int slice = xcd >> 1;                       // 0..3 (32 features each)
    int group16 = (lb >> 3) * 2 + (xcd & 1);    // 16-node group index
    int node = group16 * 16 + (threadIdx.x >> 4);
    int lane16 = threadIdx.x & 15;
    if (node >= n) return;
    int start = rs[node];
    int end = start + ((cnt[node] + 7) & ~7);
    int fbase = slice * 32 + 2 * lane16;
    const unsigned short* mrow = m + fbase;
    float a0 = 0.f, a1 = 0.f;
    for (int i = start; i < end; i += 8) {
        int s[8]; float w[8]; unsigned int v[8];
#pragma unroll
        for (int j = 0; j < 8; ++j) {
            s[j] = __builtin_nontemporal_load(cs + i + j);
            w[j] = __builtin_nontemporal_load(cw + i + j);
        }
#pragma unroll
        for (int j = 0; j < 8; ++j)
            v[j] = *(const unsigned int*)(mrow + (size_t)s[j] * 128);
#pragma unroll
        for (int j = 0; j < 8; ++j) {
            a0 += b2f((unsigned short)(v[j] & 0xffff)) * w[j];
            a1 += b2f((unsigned short)(v[j] >> 16)) * w[j];
        }
    }
    float d = di[node]; float wself = d * d;
    unsigned int v = *(const unsigned int*)(mrow + (size_t)node * 128);
    a0 += b2f((unsigned short)(v & 0xffff)) * wself + bias[fbase];
    a1 += b2f((unsigned short)(v >> 16)) * wself + bias[fbase + 1];
    union { float2 f2; double d64; } u;
    u.f2.x = a0; u.f2.y = a1;
    __builtin_nontemporal_store(u.d64, (double*)(agg + (size_t)node * 128 + fbase));
}

// ---------------- BN stats (streaming pass over agg), dual-branch ------------
__global__ __launch_bounds__(256) void stats_dual(
    const float* __restrict__ agg0, float* __restrict__ sums0, int n0, int blocksA,
    const float* __restrict__ agg1, float* __restrict__ sums1, int n1) {
    __shared__ float rsum[256], rsq[256];
    int blk = blockIdx.x;
    const float* agg; float* sums; int n, lb, nb;
    if (blk < blocksA) { agg = agg0; sums = sums0; n = n0; lb = blk; nb = blocksA; }
    else { agg = agg1; sums = sums1; n = n1; lb = blk - blocksA; nb = gridDim.x - blocksA; }
    int rpb = (n + nb - 1) / nb;
    int t = threadIdx.x;
    int f = t & 127, half = t >> 7;
    int r0 = lb * rpb, r1 = r0 + rpb; if (r1 > n) r1 = n;
    float s = 0.f, s2 = 0.f;
    for (int r = r0 + half; r < r1; r += 2) {
        float v = agg[(size_t)r * 128 + f];
        s += v; s2 += v * v;
    }
    rsum[t] = s; rsq[t] = s2;
    __syncthreads();
    if (t < 128) atomicAdd(&sums[t], rsum[t] + rsum[t + 128]);
    else atomicAdd(&sums[128 + f], rsq[f] + rsq[t]);
}

// ---------------- BN finalize+apply, dual-branch -----------------------------
__global__ __launch_bounds__(256) void apply_dual(
    const float* __restrict__ agg0, const float* __restrict__ sums0,
    const float* __restrict__ g0, const float* __restrict__ be0,
    unsigned short* __restrict__ hb0, int n0, int blocksA, int useRes,
    const float* __restrict__ agg1, const float* __restrict__ sums1,
    const float* __restrict__ g1, const float* __restrict__ be1,
    unsigned short* __restrict__ hb1, int n1) {
    __shared__ float sc[128], sh[128];
    int blk = blockIdx.x;
    const float *agg, *sums, *g, *be; unsigned short* hb; int n, lb;
    if (blk < blocksA) { agg = agg0; sums = sums0; g = g0; be = be0; hb = hb0; n = n0; lb = blk; }
    else { agg = agg1; sums = sums1; g = g1; be = be1; hb = hb1; n = n1; lb = blk - blocksA; }
    int t = threadIdx.x;
    if (t < 128) {
        float inv = 1.f / (float)n;
        float mean = sums[t] * inv;
        float var = sums[128 + t] * inv - mean * mean;
        float rstd = rsqrtf(var + EPSV);
        float s = g[t] * rstd;
        sc[t] = s;
        sh[t] = be[t] - mean * s;
    }
    __syncthreads();
    int base = lb * 1024 + t * 4;
    if (base < n * 128) {
        float4 a = *(const float4*)(agg + base);
        ushort4 h = *(const ushort4*)(hb + base);
        int f = base & 127;
        float v0 = fmaxf(a.x * sc[f] + sh[f], 0.f);
        float v1 = fmaxf(a.y * sc[f + 1] + sh[f + 1], 0.f);
        float v2 = fmaxf(a.z * sc[f + 2] + sh[f + 2], 0.f);
        float v3 = fmaxf(a.w * sc[f + 3] + sh[f + 3], 0.f);
        if (useRes) { v0 += b2f(h.x); v1 += b2f(h.y); v2 += b2f(h.z); v3 += b2f(h.w); }
        ushort4 o; o.x = f2b(v0); o.y = f2b(v1); o.z = f2b(v2); o.w = f2b(v3);
        *(ushort4*)(hb + base) = o;
    }
}

// ---------------- fused MHA + mean + residual + LayerNorm --------------------
__global__ __launch_bounds__(256) void mha_fused_kernel(
    const unsigned short* __restrict__ hbn, const unsigned short* __restrict__ hbc,
    const int* __restrict__ map,
    const unsigned short* __restrict__ WinB, const float* __restrict__ bin,
    const unsigned short* __restrict__ WoutB, const float* __restrict__ bout,
    const float* __restrict__ lng, const float* __restrict__ lnb,
    unsigned short* __restrict__ hfin, int nN, int nC) {
    __shared__ unsigned short obf_s[16 * 144];
    __shared__ float att_s[8 * 132];

    int b = blockIdx.x;
    int hg = threadIdx.x >> 6;
    int lane = threadIdx.x & 63;
    int r = lane & 15, q = lane >> 4;

    int anode = b * 8 + (r >> 1);
    if (anode >= nN) anode = nN - 1;
    const unsigned short* arow;
    if (r & 1) {
        int c = map[anode]; c = c < 0 ? 0 : (c >= nC ? nC - 1 : c);
        arow = hbc + (size_t)c * 128;
    } else {
        arow = hbn + (size_t)anode * 128;
    }
    bf16x8 afrag[4];
#pragma unroll
    for (int kc = 0; kc < 4; ++kc)
        afrag[kc] = *(const bf16x8*)(const void*)(arow + q * 8 + kc * 32);

    f32x4 qa[2], ka[2], va[2];
#pragma unroll
    for (int p = 0; p < 3; ++p) {
#pragma unroll
        for (int c = 0; c < 2; ++c) {
            int tt = p * 8 + hg * 2 + c;
            f32x4 acc = {0.f, 0.f, 0.f, 0.f};
#pragma unroll
            for (int kc = 0; kc < 4; ++kc) {
                bf16x8 bfrag = *(const bf16x8*)(const void*)(WinB + (((size_t)tt * 4 + kc) << 9) + lane * 8);
                acc = __builtin_amdgcn_mfma_f32_16x16x32_bf16(afrag[kc], bfrag, acc, 0, 0, 0);
            }
            float bv = bin[tt * 16 + r];
#pragma unroll
            for (int t = 0; t < 4; ++t) acc[t] += bv;
            if (p == 0) qa[c] = acc; else if (p == 1) ka[c] = acc; else va[c] = acc;
        }
    }

#pragma unroll
    for (int c = 0; c < 2; ++c) {
        float s00 = qa[c][0] * ka[c][0], s01 = qa[c][0] * ka[c][1];
        float s10 = qa[c][1] * ka[c][0], s11 = qa[c][1] * ka[c][1];
        float u00 = qa[c][2] * ka[c][2], u01 = qa[c][2] * ka[c][3];
        float u10 = qa[c][3] * ka[c][2], u11 = qa[c][3] * ka[c][3];
#pragma unroll
        for (int mku = 1; mku <= 8; mku <<= 1) {
            s00 += __shfl_xor(s00, mku); s01 += __shfl_xor(s01, mku);
            s10 += __shfl_xor(s10, mku); s11 += __shfl_xor(s11, mku);
            u00 += __shfl_xor(u00, mku); u01 += __shfl_xor(u01, mku);
            u10 += __shfl_xor(u10, mku); u11 += __shfl_xor(u11, mku);
        }
        s00 *= 0.25f; s01 *= 0.25f; s10 *= 0.25f; s11 *= 0.25f;
        u00 *= 0.25f; u01 *= 0.25f; u10 *= 0.25f; u11 *= 0.25f;
        float m0 = fmaxf(s00, s01), m1 = fmaxf(s10, s11);
        float m2 = fmaxf(u00, u01), m3 = fmaxf(u10, u11);
        float e00 = __expf(s00 - m0), e01 = __expf(s01 - m0);
        float e10 = __expf(s10 - m1), e11 = __expf(s11 - m1);
        float f00 = __expf(u00 - m2), f01 = __expf(u01 - m2);
        float f10 = __expf(u10 - m3), f11 = __expf(u11 - m3);
        float i0 = 1.f / (e00 + e01), i1 = 1.f / (e10 + e11);
        float i2 = 1.f / (f00 + f01), i3 = 1.f / (f10 + f11);
        float o0 = (e00 * va[c][0] + e01 * va[c][1]) * i0;
        float o1 = (e10 * va[c][0] + e11 * va[c][1]) * i1;
        float o2 = (f00 * va[c][2] + f01 * va[c][3]) * i2;
        float o3 = (f10 * va[c][2] + f11 * va[c][3]) * i3;
        int ocol = (hg * 2 + c) * 16 + r;
        obf_s[(q * 4 + 0) * 144 + ocol] = f2b(o0);
        obf_s[(q * 4 + 1) * 144 + ocol] = f2b(o1);
        obf_s[(q * 4 + 2) * 144 + ocol] = f2b(o2);
        obf_s[(q * 4 + 3) * 144 + ocol] = f2b(o3);
    }
    __syncthreads();

    bf16x8 ofrag[4];
#pragma unroll
    for (int kc = 0; kc < 4; ++kc)
        ofrag[kc] = *(const bf16x8*)(const void*)(obf_s + r * 144 + q * 8 + kc * 32);
#pragma unroll
    for (int c = 0; c < 2; ++c) {
        int tt = hg * 2 + c;
        f32x4 acc = {0.f, 0.f, 0.f, 0.f};
#pragma unroll
        for (int kc = 0; kc < 4; ++kc) {
            bf16x8 bfrag = *(const bf16x8*)(const void*)(WoutB + (((size_t)tt * 4 + kc) << 9) + lane * 8);
            acc = __builtin_amdgcn_mfma_f32_16x16x32_bf16(ofrag[kc], bfrag, acc, 0, 0, 0);
        }
        int n0 = tt * 16;
        float bv = bout[n0 + r];
        att_s[(q * 2 + 0) * 132 + n0 + r] = 0.5f * (acc[0] + acc[1]) + bv;
        att_s[(q * 2 + 1) * 132 + n0 + r] = 0.5f * (acc[2] + acc[3]) + bv;
    }
    __syncthreads();

    {
        int nl = threadIdx.x >> 5;
        int j2 = threadIdx.x & 31;
        int gnode = b * 8 + nl; if (gnode >= nN) gnode = nN - 1;
        const unsigned short* hrow = hbn + (size_t)gnode * 128 + j2 * 4;
        float x[4]; float s = 0.f, s2 = 0.f;
#pragma unroll
        for (int i = 0; i < 4; ++i) {
            x[i] = att_s[nl * 132 + j2 * 4 + i] + b2f(hrow[i]);
            s += x[i]; s2 += x[i] * x[i];
        }
        s += __shfl_xor(s, 1);  s2 += __shfl_xor(s2, 1);
        s += __shfl_xor(s, 2);  s2 += __shfl_xor(s2, 2);
        s += __shfl_xor(s, 4);  s2 += __shfl_xor(s2, 4);
        s += __shfl_xor(s, 8);  s2 += __shfl_xor(s2, 8);
        s += __shfl_xor(s, 16); s2 += __shfl_xor(s2, 16);
        float mu = s * (1.f / 128.f);
        float var = s2 * (1.f / 128.f) - mu * mu;
        float rstd = rsqrtf(var + EPSV);
        ushort4 o;
        o.x = f2b((x[0] - mu) * rstd * lng[j2 * 4]     + lnb[j2 * 4]);
        o.y = f2b((x[1] - mu) * rstd * lng[j2 * 4 + 1] + lnb[j2 * 4 + 1]);
        o.z = f2b((x[2] - mu) * rstd * lng[j2 * 4 + 2] + lnb[j2 * 4 + 2]);
        o.w = f2b((x[3] - mu) * rstd * lng[j2 * 4 + 3] + lnb[j2 * 4 + 3]);
        *(ushort4*)(hfin + (size_t)gnode * 128 + j2 * 4) = o;
    }
}

// ---------------- classifier stats (F=64) ----------------
__global__ __launch_bounds__(256) void stats64_kernel(const float* __restrict__ z,
                                                      float* __restrict__ sums, int N) {
    __shared__ float ls[4][64], lsq[4][64];
    int f = threadIdx.x & 63, rg = threadIdx.x >> 6;
    int r0 = blockIdx.x * 64 + rg * 16;
    int r1 = r0 + 16; if (r1 > N) r1 = N;
    float s = 0.f, s2 = 0.f;
    for (int r = r0; r < r1; ++r) {
        float v = z[(size_t)r * 64 + f];
        s += v; s2 += v * v;
    }
    ls[rg][f] = s; lsq[rg][f] = s2;
    __syncthreads();
    int t = threadIdx.x;
    if (t < 64) atomicAdd(&sums[t], ls[0][t] + ls[1][t] + ls[2][t] + ls[3][t]);
    else if (t < 128) { int c = t - 64; atomicAdd(&sums[64 + c], lsq[0][c] + lsq[1][c] + lsq[2][c] + lsq[3][c]); }
}

// ---------------- final: BN(inline finalize)+ReLU+Linear(64,10)+log_softmax --
__global__ __launch_bounds__(256) void final_kernel(const float* __restrict__ z,
                                                    const float* __restrict__ sums,
                                                    const float* __restrict__ g,
                                                    const float* __restrict__ be,
                                                    const float* __restrict__ W2,
                                                    const float* __restrict__ b2v,
                                                    float* __restrict__ out, int nN) {
    int node = blockIdx.x * 4 + (threadIdx.x >> 6);
    int lane = threadIdx.x & 63;
    float inv = 1.f / (float)nN;
    float mean = sums[lane] * inv;
    float var = sums[64 + lane] * inv - mean * mean;
    float sc = g[lane] * rsqrtf(var + EPSV);
    float sh = be[lane] - mean * sc;
    float v = 0.f;
    if (node < nN) v = fmaxf(z[(size_t)node * 64 + lane] * sc + sh, 0.f);
    float p[10];
    const float* wrow = W2 + lane * 10;
#pragma unroll
    for (int c = 0; c < 10; ++c) p[c] = v * wrow[c];
#pragma unroll
    for (int off = 32; off >= 1; off >>= 1) {
#pragma unroll
        for (int c = 0; c < 10; ++c) p[c] += __shfl_xor(p[c], off);
    }
    if (node >= nN) return;
    float l[10], mx = -1e30f;
#pragma unroll
    for (int c = 0; c < 10; ++c) { l[c] = p[c] + b2v[c]; mx = fmaxf(mx, l[c]); }
    float se = 0.f;
#pragma unroll
    for (int c = 0; c < 10; ++c) se += expf(l[c] - mx);
    float lse = mx + logf(se);
    if (lane < 10) out[(size_t)node * 10 + lane] = l[lane] - lse;
}

// ---------------------------------------------------------------------------
static inline int cdiv(long a, long b) { return (int)((a + b - 1) / b); }

extern "C" void kernel_launch(void* const* d_in, const int* in_sizes, int n_in,
                              void* d_out, int out_size, void* d_ws, size_t ws_size,
                              hipStream_t stream) {
    const float* node_feat = (const float*)d_in[0];
    const int*   nedge     = (const int*)d_in[1];
    const float* comm_feat = (const float*)d_in[2];
    const int*   cedge     = (const int*)d_in[3];
    const int*   n2c       = (const int*)d_in[4];
    const float* node_W    = (const float*)d_in[5];
    const float* node_b    = (const float*)d_in[6];
    const float* node_g    = (const float*)d_in[7];
    const float* node_beta = (const float*)d_in[8];
    const float* comm_W    = (const float*)d_in[9];
    const float* comm_b    = (const float*)d_in[10];
    const float* comm_g    = (const float*)d_in[11];
    const float* comm_beta = (const float*)d_in[12];
    const float* attn_in_w = (const float*)d_in[13];
    const float* attn_in_b = (const float*)d_in[14];
    const float* attn_out_w= (const float*)d_in[15];
    const float* attn_out_b= (const float*)d_in[16];
    const float* ln_g      = (const float*)d_in[17];
    const float* ln_b      = (const float*)d_in[18];
    const float* cls_W1    = (const float*)d_in[19];
    const float* cls_b1    = (const float*)d_in[20];
    const float* cls_bn_g  = (const float*)d_in[21];
    const float* cls_bn_b  = (const float*)d_in[22];
    const float* cls_W2    = (const float*)d_in[23];
    const float* cls_b2    = (const float*)d_in[24];

    const int nN = in_sizes[0] / 128;
    const int nE = in_sizes[1] / 2;
    const int nC = in_sizes[2] / 128;
    const int cE = in_sizes[3] / 2;
    const int padE_n = nE + 8 * nN;
    const int padE_c = cE + 8 * nC;

    char* ws = (char*)d_ws;
    size_t off = 0;
    auto alloc = [&](size_t bytes) -> char* {
        char* p = ws + off;
        off = (off + bytes + 255) & ~(size_t)255;
        return p;
    };
    // ---- contiguous zero region (single memset) ----
    size_t zero_begin = off;
    int*   cnt_n  = (int*)alloc((size_t)nN * 4);
    int*   cur_n  = (int*)alloc((size_t)nN * 4);
    int*   cnt_c  = (int*)alloc((size_t)nC * 4);
    int*   cur_c  = (int*)alloc((size_t)nC * 4);
    float* gsums  = (float*)alloc((size_t)6 * 256 * 4);
    float* csums  = (float*)alloc(128 * 4);
    int*   csrc_n = (int*)alloc((size_t)padE_n * 4);
    float* cw_n   = (float*)alloc((size_t)padE_n * 4);
    int*   csrc_c = (int*)alloc((size_t)padE_c * 4);
    float* cw_c   = (float*)alloc((size_t)padE_c * 4);
    size_t zero_bytes = off - zero_begin;
    // ---- CSR aux ----
    int*   rs_n   = (int*)alloc((size_t)(nN + 1) * 4);
    int*   bsum_n = (int*)alloc(256 * 4);
    float* dinv_n = (float*)alloc((size_t)nN * 4);
    int*   rs_c   = (int*)alloc((size_t)(nC + 1) * 4);
    int*   bsum_c = (int*)alloc(256 * 4);
    float* dinv_c = (float*)alloc((size_t)nC * 4);
    // ---- activations / weights ----
    unsigned short* hb_n  = (unsigned short*)alloc((size_t)nN * 256);
    unsigned short* hb_c  = (unsigned short*)alloc((size_t)nC * 256);
    unsigned short* cfb   = (unsigned short*)alloc((size_t)nC * 256);
    unsigned short* m_cb  = (unsigned short*)alloc((size_t)nC * 256);
    float*          agg_c = (float*)alloc((size_t)nC * 512);
    unsigned short* WtN  = (unsigned short*)alloc((size_t)3 * 16384 * 2);
    unsigned short* WtC  = (unsigned short*)alloc((size_t)3 * 16384 * 2);
    unsigned short* W1t  = (unsigned short*)alloc((size_t)64 * 128 * 2);
    unsigned short* WinB = (unsigned short*)alloc((size_t)384 * 128 * 2);
    unsigned short* WoutB= (unsigned short*)alloc((size_t)128 * 128 * 2);
    unsigned short* m_nb = (unsigned short*)alloc((size_t)nN * 256);
    float*          agg_n= (float*)alloc((size_t)nN * 512);
    // aliases (disjoint liveness)
    unsigned short* nfb  = (unsigned short*)agg_n;
    unsigned short* hfin = m_nb;
    float*          z    = agg_n;

    hipMemsetAsync(ws + zero_begin, 0, zero_bytes, stream);

    // ---- prep ----
    long prepN = 49152L * 3 + 8192 + 16384 + (long)nC * 128 + (long)nN * 128;
    prep_kernel<<<cdiv(prepN, 256), 256, 0, stream>>>(
        node_W, comm_W, cls_W1, attn_in_w, attn_out_w, comm_feat, node_feat,
        WtN, WtC, W1t, WinB, WoutB, cfb, nfb, nC * 128, nN * 128);

    // ---- CSR build (rows padded to x8) ----
    count_dual<<<cdiv((long)nE + cE, 256), 256, 0, stream>>>(nedge + nE, cnt_n, nE, cedge + cE, cnt_c, cE);
    dinv_dual<<<cdiv((long)nN + nC, 256), 256, 0, stream>>>(cnt_n, dinv_n, nN, cnt_c, dinv_c, nC);
    int nbN = cdiv(nN, 1024), nbC = cdiv(nC, 1024);
    scan_block_dual<<<nbN + nbC, 1024, 0, stream>>>(cnt_n, rs_n, bsum_n, nN, nbN, cnt_c, rs_c, bsum_c, nC);
    scan_sums_dual<<<1, 64, 0, stream>>>(bsum_n, nbN, bsum_c, nbC);
    scan_add_dual<<<cdiv((long)nN + nC, 256), 256, 0, stream>>>(rs_n, bsum_n, nN, rs_c, bsum_c, nC);
    fill_dual<<<cdiv((long)nE + cE, 256), 256, 0, stream>>>(
        nedge, nedge + nE, dinv_n, rs_n, cur_n, csrc_n, cw_n, nE,
        cedge, cedge + cE, dinv_c, rs_c, cur_c, csrc_c, cw_c, cE);

    // ---- GCN layers ----
    int gemmA = cdiv(nN, 64), gemmB = cdiv(nC, 64);
    // sliced gather: 16-node groups, 2 groups per 8-block stripe x 4 slices
    int gatA = cdiv(cdiv(nN, 16), 2) * 8;
    int gatB = cdiv(cdiv(nC, 16), 2) * 8;
    int appA = cdiv((long)nN * 128, 1024), appB = cdiv((long)nC * 128, 1024);
    for (int i = 0; i < 3; ++i) {
        const unsigned short* A0 = i == 0 ? nfb : hb_n;
        const unsigned short* A1 = i == 0 ? cfb : hb_c;
        float* s0 = gsums + (size_t)(i * 2 + 0) * 256;
        float* s1 = gsums + (size_t)(i * 2 + 1) * 256;
        gemm_dual<<<gemmA + gemmB, 256, 0, stream>>>(
            A0, WtN + i * 16384, m_nb, nN, gemmA,
            A1, WtC + i * 16384, m_cb, nC);
        gather_dual<<<gatA + gatB, 256, 0, stream>>>(
            m_nb, rs_n, cnt_n, csrc_n, cw_n, dinv_n, node_b + i * 128, agg_n, nN, gatA,
            m_cb, rs_c, cnt_c, csrc_c, cw_c, dinv_c, comm_b + i * 128, agg_c, nC);
        stats_dual<<<256 + 4, 256, 0, stream>>>(agg_n, s0, nN, 256, agg_c, s1, nC);
        apply_dual<<<appA + appB, 256, 0, stream>>>(
            agg_n, s0, node_g + i * 128, node_beta + i * 128, hb_n, nN, appA, i > 0 ? 1 : 0,
            agg_c, s1, comm_g + i * 128, comm_beta + i * 128, hb_c, nC);
    }

    // ---- fused MHA + mean + residual + LN ----
    mha_fused_kernel<<<cdiv(nN, 8), 256, 0, stream>>>(
        hb_n, hb_c, n2c, WinB, attn_in_b, WoutB, attn_out_b, ln_g, ln_b, hfin, nN, nC);

    // ---- classifier ----
    int waves1 = (nN + 15) / 16;
    gemm_kernel<<<cdiv((long)waves1 * 64, 256), 256, 0, stream>>>(
        hfin, W1t, cls_b1, z, nN, 64);
    stats64_kernel<<<cdiv(nN, 64), 256, 0, stream>>>(z, csums, nN);
    final_kernel<<<cdiv(nN, 4), 256, 0, stream>>>(z, csums, cls_bn_g, cls_bn_b,
                                                  cls_W2, cls_b2, (float*)d_out, nN);
}

// Round 13
// 553.812 us; speedup vs baseline: 1.1754x; 1.1754x over previous
//
#include <hip/hip_runtime.h>
#include <hip/hip_bf16.h>
#include <cstdint>
#include <cstddef>

// ---------------------------------------------------------------------------
// ImprovedCrossScaleGNN on MI355X (gfx950).
// Inputs float32 + int32, output float32. bf16 MFMA GEMMs, f32 stats.
// R12->R13: REVERT XCD-sliced gather (regressed 544->651; block->XCD
// heuristic + nontemporal agg stores backfired). Back to R11 wave-per-node
// gather, refined: (src,weight) packed as int2 (one 8B load per edge) and
// uint2 row loads (32 lanes x 2 edge-slots per wave; epair partials merged
// via shfl_xor 32). Same 8 rows in flight, half the load instructions.
// ---------------------------------------------------------------------------

typedef __attribute__((ext_vector_type(8))) short bf16x8;
typedef __attribute__((ext_vector_type(4))) float f32x4;

#define EPSV 1e-5f

__device__ __forceinline__ float b2f(unsigned short u) {
    union { unsigned int i; float f; } x; x.i = ((unsigned int)u) << 16; return x.f;
}
__device__ __forceinline__ unsigned short f2b(float f) {
    union { float f; unsigned int i; } x; x.f = f;
    unsigned int i = x.i;
    return (unsigned short)((i + 0x7fffu + ((i >> 16) & 1u)) >> 16);
}

// ---------------- prep: weights -> fragment-linear bf16 + feature casts ------
__global__ void prep_kernel(const float* __restrict__ node_W, const float* __restrict__ comm_W,
                            const float* __restrict__ cls_W1, const float* __restrict__ attn_in_w,
                            const float* __restrict__ attn_out_w, const float* __restrict__ comm_feat,
                            const float* __restrict__ node_feat,
                            unsigned short* __restrict__ WtN, unsigned short* __restrict__ WtC,
                            unsigned short* __restrict__ W1t, unsigned short* __restrict__ WinB,
                            unsigned short* __restrict__ WoutB, unsigned short* __restrict__ cfb,
                            unsigned short* __restrict__ nfb, int nC128, int nN128) {
    int idx = blockIdx.x * 256 + threadIdx.x;
    if (idx < 49152) {
        int l = idx >> 14, e = idx & 16383;
        int j = e & 7, lane = (e >> 3) & 63, kc = (e >> 9) & 3, t = e >> 11;
        int col = t * 16 + (lane & 15);
        int k = (lane >> 4) * 8 + kc * 32 + j;
        WtN[idx] = f2b(node_W[l * 16384 + k * 128 + col]); return;
    }
    idx -= 49152;
    if (idx < 49152) {
        int l = idx >> 14, e = idx & 16383;
        int j = e & 7, lane = (e >> 3) & 63, kc = (e >> 9) & 3, t = e >> 11;
        int col = t * 16 + (lane & 15);
        int k = (lane >> 4) * 8 + kc * 32 + j;
        WtC[idx] = f2b(comm_W[l * 16384 + k * 128 + col]); return;
    }
    idx -= 49152;
    if (idx < 8192) {
        int e = idx;
        int j = e & 7, lane = (e >> 3) & 63, kc = (e >> 9) & 3, t = e >> 11;
        int col = t * 16 + (lane & 15);
        int k = (lane >> 4) * 8 + kc * 32 + j;
        W1t[idx] = f2b(cls_W1[k * 64 + col]); return;
    }
    idx -= 8192;
    if (idx < 49152) {
        int e = idx;
        int j = e & 7, lane = (e >> 3) & 63, kc = (e >> 9) & 3, t = e >> 11;
        int col = t * 16 + (lane & 15);
        int k = (lane >> 4) * 8 + kc * 32 + j;
        WinB[idx] = f2b(attn_in_w[col * 128 + k]); return;
    }
    idx -= 49152;
    if (idx < 16384) {
        int e = idx;
        int j = e & 7, lane = (e >> 3) & 63, kc = (e >> 9) & 3, t = e >> 11;
        int col = t * 16 + (lane & 15);
        int k = (lane >> 4) * 8 + kc * 32 + j;
        WoutB[idx] = f2b(attn_out_w[col * 128 + k]); return;
    }
    idx -= 16384;
    if (idx < nC128) { cfb[idx] = f2b(comm_feat[idx]); return; }
    idx -= nC128;
    if (idx < nN128) { nfb[idx] = f2b(node_feat[idx]); }
}

// ---------------- CSR build (dual) ----------------
__global__ void count_dual(const int* __restrict__ nd, int* __restrict__ cnt_n, int nE,
                           const int* __restrict__ cd, int* __restrict__ cnt_c, int cE) {
    int t = blockIdx.x * 256 + threadIdx.x;
    if (t < nE) atomicAdd(&cnt_n[nd[t]], 1);
    else if (t - nE < cE) atomicAdd(&cnt_c[cd[t - nE]], 1);
}

__global__ void dinv_dual(const int* __restrict__ cnt_n, float* __restrict__ di_n, int nN,
                          const int* __restrict__ cnt_c, float* __restrict__ di_c, int nC) {
    int t = blockIdx.x * 256 + threadIdx.x;
    if (t < nN) di_n[t] = rsqrtf((float)cnt_n[t] + 1.0f);
    else if (t - nN < nC) di_c[t - nN] = rsqrtf((float)cnt_c[t - nN] + 1.0f);
}

// scans PADDED counts: ceil8(cnt)
__global__ void scan_block_dual(const int* __restrict__ cnt_n, int* __restrict__ rs_n,
                                int* __restrict__ bsum_n, int nN, int nbN,
                                const int* __restrict__ cnt_c, int* __restrict__ rs_c,
                                int* __restrict__ bsum_c, int nC) {
    __shared__ int tmp[2048];
    const int* cnt; int* excl; int* bsum; int n, lb;
    if ((int)blockIdx.x < nbN) { cnt = cnt_n; excl = rs_n; bsum = bsum_n; n = nN; lb = blockIdx.x; }
    else { cnt = cnt_c; excl = rs_c; bsum = bsum_c; n = nC; lb = blockIdx.x - nbN; }
    int tid = threadIdx.x;
    int gid = lb * 1024 + tid;
    int v = (gid < n) ? ((cnt[gid] + 7) & ~7) : 0;
    int buf = 0;
    tmp[tid] = v;
    __syncthreads();
    for (int d = 1; d < 1024; d <<= 1) {
        int t = tmp[buf * 1024 + tid];
        int add = (tid >= d) ? tmp[buf * 1024 + tid - d] : 0;
        tmp[(1 - buf) * 1024 + tid] = t + add;
        buf = 1 - buf;
        __syncthreads();
    }
    int inc = tmp[buf * 1024 + tid];
    if (gid < n) excl[gid] = inc - v;
    if (tid == 1023) bsum[lb] = inc;
}

__global__ void scan_sums_dual(int* __restrict__ bsum_n, int nbN,
                               int* __restrict__ bsum_c, int nbC) {
    if (threadIdx.x == 0) {
        int acc = 0;
        for (int i = 0; i < nbN; ++i) { int t = bsum_n[i]; bsum_n[i] = acc; acc += t; }
    } else if (threadIdx.x == 1) {
        int acc = 0;
        for (int i = 0; i < nbC; ++i) { int t = bsum_c[i]; bsum_c[i] = acc; acc += t; }
    }
}

__global__ void scan_add_dual(int* __restrict__ rs_n, const int* __restrict__ bsum_n, int nN,
                              int* __restrict__ rs_c, const int* __restrict__ bsum_c, int nC) {
    int gid = blockIdx.x * 256 + threadIdx.x;
    if (gid < nN) rs_n[gid] += bsum_n[gid >> 10];
    else {
        int g = gid - nN;
        if (g < nC) rs_c[g] += bsum_c[g >> 10];
    }
}

// writes packed (src, weight) per edge slot
__global__ void fill_dual(const int* __restrict__ ns, const int* __restrict__ ndst,
                          const float* __restrict__ di_n, const int* __restrict__ rs_n,
                          int* __restrict__ cur_n, int2* __restrict__ ew_n, int nE,
                          const int* __restrict__ cs, const int* __restrict__ cdst,
                          const float* __restrict__ di_c, const int* __restrict__ rs_c,
                          int* __restrict__ cur_c, int2* __restrict__ ew_c, int cE) {
    int e = blockIdx.x * 256 + threadIdx.x;
    if (e < nE) {
        int s = ns[e], d = ndst[e];
        int pos = atomicAdd(&cur_n[d], 1);
        int slot = rs_n[d] + pos;
        int2 p; p.x = s; p.y = __float_as_int(di_n[s] * di_n[d]);
        ew_n[slot] = p;
    } else if (e - nE < cE) {
        int ee = e - nE;
        int s = cs[ee], d = cdst[ee];
        int pos = atomicAdd(&cur_c[d], 1);
        int slot = rs_c[d] + pos;
        int2 p; p.x = s; p.y = __float_as_int(di_c[s] * di_c[d]);
        ew_c[slot] = p;
    }
}

// ---------------- MFMA GEMM wave body: 16 rows x 128 cols, bf16 out ----------
__device__ __forceinline__ void gemm_wave_128(const unsigned short* __restrict__ A,
                                              const unsigned short* __restrict__ Bt,
                                              unsigned short* __restrict__ D,
                                              int M, int m0, int lane) {
    int r = lane & 15, q = lane >> 4;
    int arow = m0 + r; if (arow >= M) arow = M - 1;
    const unsigned short* ap = A + (size_t)arow * 128 + q * 8;
    bf16x8 afrag[4];
#pragma unroll
    for (int kc = 0; kc < 4; ++kc)
        afrag[kc] = *(const bf16x8*)(const void*)(ap + kc * 32);
#pragma unroll
    for (int tt = 0; tt < 8; ++tt) {
        f32x4 acc = {0.f, 0.f, 0.f, 0.f};
#pragma unroll
        for (int kc = 0; kc < 4; ++kc) {
            bf16x8 bfrag = *(const bf16x8*)(const void*)(Bt + (((size_t)tt * 4 + kc) << 9) + lane * 8);
            acc = __builtin_amdgcn_mfma_f32_16x16x32_bf16(afrag[kc], bfrag, acc, 0, 0, 0);
        }
        int n0 = tt * 16;
#pragma unroll
        for (int t = 0; t < 4; ++t) {
            int row = m0 + q * 4 + t;
            if (row < M) D[(size_t)row * 128 + n0 + r] = f2b(acc[t]);
        }
    }
}

__global__ __launch_bounds__(256) void gemm_dual(
    const unsigned short* __restrict__ A0, const unsigned short* __restrict__ Bt0,
    unsigned short* __restrict__ D0, int M0, int blocksA,
    const unsigned short* __restrict__ A1, const unsigned short* __restrict__ Bt1,
    unsigned short* __restrict__ D1, int M1) {
    int blk = blockIdx.x;
    const unsigned short *A, *Bt; unsigned short* D; int M, lb;
    if (blk < blocksA) { A = A0; Bt = Bt0; D = D0; M = M0; lb = blk; }
    else { A = A1; Bt = Bt1; D = D1; M = M1; lb = blk - blocksA; }
    int m0 = (lb * 4 + (int)(threadIdx.x >> 6)) * 16;
    if (m0 >= M) return;
    gemm_wave_128(A, Bt, D, M, m0, threadIdx.x & 63);
}

// classifier GEMM (generic Ncol, f32 out, bias); Bt fragment-linear
__global__ void gemm_kernel(const unsigned short* __restrict__ A,
                            const unsigned short* __restrict__ Bt,
                            const float* __restrict__ bias,
                            float* __restrict__ D, int M, int Ncol) {
    int wave = (blockIdx.x * blockDim.x + threadIdx.x) >> 6;
    int lane = threadIdx.x & 63;
    int m0 = wave * 16;
    if (m0 >= M) return;
    int r = lane & 15, q = lane >> 4;
    int arow = m0 + r; if (arow >= M) arow = M - 1;
    const unsigned short* ap = A + (size_t)arow * 128 + q * 8;
    bf16x8 afrag[4];
#pragma unroll
    for (int kc = 0; kc < 4; ++kc)
        afrag[kc] = *(const bf16x8*)(const void*)(ap + kc * 32);
    int ntiles = Ncol >> 4;
    for (int tt = 0; tt < ntiles; ++tt) {
        f32x4 acc = {0.f, 0.f, 0.f, 0.f};
#pragma unroll
        for (int kc = 0; kc < 4; ++kc) {
            bf16x8 bfrag = *(const bf16x8*)(const void*)(Bt + (((size_t)tt * 4 + kc) << 9) + lane * 8);
            acc = __builtin_amdgcn_mfma_f32_16x16x32_bf16(afrag[kc], bfrag, acc, 0, 0, 0);
        }
        int n0 = tt * 16;
        float bv = bias[n0 + r];
#pragma unroll
        for (int t = 0; t < 4; ++t) {
            int row = m0 + q * 4 + t;
            if (row < M) D[(size_t)row * Ncol + n0 + r] = acc[t] + bv;
        }
    }
}

// ---------------- gather (CSR, rows padded x8), dual-branch ------------------
// Wave per node. 32 lanes cover a 256B row (uint2 = 4 bf16 feats/lane);
// epair = lane>>5 walks even/odd edge slots -> 8 rows in flight with half
// the load instructions of R11. epair partials merged via shfl_xor(.,32).
__global__ __launch_bounds__(256) void gather_dual(
    const unsigned short* __restrict__ m0, const int* __restrict__ rs0,
    const int* __restrict__ cnt0, const int2* __restrict__ ew0,
    const float* __restrict__ di0, const float* __restrict__ b0,
    float* __restrict__ agg0, int n0, int blocksA,
    const unsigned short* __restrict__ m1, const int* __restrict__ rs1,
    const int* __restrict__ cnt1, const int2* __restrict__ ew1,
    const float* __restrict__ di1, const float* __restrict__ b1,
    float* __restrict__ agg1, int n1) {
    int blk = blockIdx.x;
    const unsigned short* m; const int *rs, *cnt; const int2* ew;
    const float *di, *bias; float *agg; int n, lb;
    if (blk < blocksA) { m = m0; rs = rs0; cnt = cnt0; ew = ew0; di = di0; bias = b0; agg = agg0; n = n0; lb = blk; }
    else { m = m1; rs = rs1; cnt = cnt1; ew = ew1; di = di1; bias = b1; agg = agg1; n = n1; lb = blk - blocksA; }
    int wib = threadIdx.x >> 6, lane = threadIdx.x & 63;
    int node = lb * 4 + wib;
    if (node >= n) return;
    int start = rs[node];
    int end = start + ((cnt[node] + 7) & ~7);
    int epair = lane >> 5, hl = lane & 31;
    const unsigned short* mcol = m + 4 * hl;     // 4 feats per lane
    float a0 = 0.f, a1 = 0.f, a2 = 0.f, a3 = 0.f;
    for (int i = start; i < end; i += 8) {
        int2 e[4]; uint2 v[4];
#pragma unroll
        for (int j = 0; j < 4; ++j) e[j] = ew[i + 2 * j + epair];
#pragma unroll
        for (int j = 0; j < 4; ++j)
            v[j] = *(const uint2*)(mcol + (size_t)e[j].x * 128);
#pragma unroll
        for (int j = 0; j < 4; ++j) {
            float w = __int_as_float(e[j].y);
            a0 += b2f((unsigned short)(v[j].x & 0xffff)) * w;
            a1 += b2f((unsigned short)(v[j].x >> 16)) * w;
            a2 += b2f((unsigned short)(v[j].y & 0xffff)) * w;
            a3 += b2f((unsigned short)(v[j].y >> 16)) * w;
        }
    }
    a0 += __shfl_xor(a0, 32); a1 += __shfl_xor(a1, 32);
    a2 += __shfl_xor(a2, 32); a3 += __shfl_xor(a3, 32);
    if (epair == 0) {
        float d = di[node]; float wself = d * d;
        uint2 v = *(const uint2*)(mcol + (size_t)node * 128);
        a0 += b2f((unsigned short)(v.x & 0xffff)) * wself + bias[4 * hl];
        a1 += b2f((unsigned short)(v.x >> 16)) * wself + bias[4 * hl + 1];
        a2 += b2f((unsigned short)(v.y & 0xffff)) * wself + bias[4 * hl + 2];
        a3 += b2f((unsigned short)(v.y >> 16)) * wself + bias[4 * hl + 3];
        float4 o; o.x = a0; o.y = a1; o.z = a2; o.w = a3;
        *(float4*)(agg + (size_t)node * 128 + 4 * hl) = o;
    }
}

// ---------------- BN stats (streaming pass over agg), dual-branch ------------
__global__ __launch_bounds__(256) void stats_dual(
    const float* __restrict__ agg0, float* __restrict__ sums0, int n0, int blocksA,
    const float* __restrict__ agg1, float* __restrict__ sums1, int n1) {
    __shared__ float rsum[256], rsq[256];
    int blk = blockIdx.x;
    const float* agg; float* sums; int n, lb, nb;
    if (blk < blocksA) { agg = agg0; sums = sums0; n = n0; lb = blk; nb = blocksA; }
    else { agg = agg1; sums = sums1; n = n1; lb = blk - blocksA; nb = gridDim.x - blocksA; }
    int rpb = (n + nb - 1) / nb;
    int t = threadIdx.x;
    int f = t & 127, half = t >> 7;
    int r0 = lb * rpb, r1 = r0 + rpb; if (r1 > n) r1 = n;
    float s = 0.f, s2 = 0.f;
    for (int r = r0 + half; r < r1; r += 2) {
        float v = agg[(size_t)r * 128 + f];
        s += v; s2 += v * v;
    }
    rsum[t] = s; rsq[t] = s2;
    __syncthreads();
    if (t < 128) atomicAdd(&sums[t], rsum[t] + rsum[t + 128]);
    else atomicAdd(&sums[128 + f], rsq[f] + rsq[t]);
}

// ---------------- BN finalize+apply, dual-branch -----------------------------
__global__ __launch_bounds__(256) void apply_dual(
    const float* __restrict__ agg0, const float* __restrict__ sums0,
    const float* __restrict__ g0, const float* __restrict__ be0,
    unsigned short* __restrict__ hb0, int n0, int blocksA, int useRes,
    const float* __restrict__ agg1, const float* __restrict__ sums1,
    const float* __restrict__ g1, const float* __restrict__ be1,
    unsigned short* __restrict__ hb1, int n1) {
    __shared__ float sc[128], sh[128];
    int blk = blockIdx.x;
    const float *agg, *sums, *g, *be; unsigned short* hb; int n, lb;
    if (blk < blocksA) { agg = agg0; sums = sums0; g = g0; be = be0; hb = hb0; n = n0; lb = blk; }
    else { agg = agg1; sums = sums1; g = g1; be = be1; hb = hb1; n = n1; lb = blk - blocksA; }
    int t = threadIdx.x;
    if (t < 128) {
        float inv = 1.f / (float)n;
        float mean = sums[t] * inv;
        float var = sums[128 + t] * inv - mean * mean;
        float rstd = rsqrtf(var + EPSV);
        float s = g[t] * rstd;
        sc[t] = s;
        sh[t] = be[t] - mean * s;
    }
    __syncthreads();
    int base = lb * 1024 + t * 4;
    if (base < n * 128) {
        float4 a = *(const float4*)(agg + base);
        ushort4 h = *(const ushort4*)(hb + base);
        int f = base & 127;
        float v0 = fmaxf(a.x * sc[f] + sh[f], 0.f);
        float v1 = fmaxf(a.y * sc[f + 1] + sh[f + 1], 0.f);
        float v2 = fmaxf(a.z * sc[f + 2] + sh[f + 2], 0.f);
        float v3 = fmaxf(a.w * sc[f + 3] + sh[f + 3], 0.f);
        if (useRes) { v0 += b2f(h.x); v1 += b2f(h.y); v2 += b2f(h.z); v3 += b2f(h.w); }
        ushort4 o; o.x = f2b(v0); o.y = f2b(v1); o.z = f2b(v2); o.w = f2b(v3);
        *(ushort4*)(hb + base) = o;
    }
}

// ---------------- fused MHA + mean + residual + LayerNorm --------------------
__global__ __launch_bounds__(256) void mha_fused_kernel(
    const unsigned short* __restrict__ hbn, const unsigned short* __restrict__ hbc,
    const int* __restrict__ map,
    const unsigned short* __restrict__ WinB, const float* __restrict__ bin,
    const unsigned short* __restrict__ WoutB, const float* __restrict__ bout,
    const float* __restrict__ lng, const float* __restrict__ lnb,
    unsigned short* __restrict__ hfin, int nN, int nC) {
    __shared__ unsigned short obf_s[16 * 144];
    __shared__ float att_s[8 * 132];

    int b = blockIdx.x;
    int hg = threadIdx.x >> 6;
    int lane = threadIdx.x & 63;
    int r = lane & 15, q = lane >> 4;

    int anode = b * 8 + (r >> 1);
    if (anode >= nN) anode = nN - 1;
    const unsigned short* arow;
    if (r & 1) {
        int c = map[anode]; c = c < 0 ? 0 : (c >= nC ? nC - 1 : c);
        arow = hbc + (size_t)c * 128;
    } else {
        arow = hbn + (size_t)anode * 128;
    }
    bf16x8 afrag[4];
#pragma unroll
    for (int kc = 0; kc < 4; ++kc)
        afrag[kc] = *(const bf16x8*)(const void*)(arow + q * 8 + kc * 32);

    f32x4 qa[2], ka[2], va[2];
#pragma unroll
    for (int p = 0; p < 3; ++p) {
#pragma unroll
        for (int c = 0; c < 2; ++c) {
            int tt = p * 8 + hg * 2 + c;
            f32x4 acc = {0.f, 0.f, 0.f, 0.f};
#pragma unroll
            for (int kc = 0; kc < 4; ++kc) {
                bf16x8 bfrag = *(const bf16x8*)(const void*)(WinB + (((size_t)tt * 4 + kc) << 9) + lane * 8);
                acc = __builtin_amdgcn_mfma_f32_16x16x32_bf16(afrag[kc], bfrag, acc, 0, 0, 0);
            }
            float bv = bin[tt * 16 + r];
#pragma unroll
            for (int t = 0; t < 4; ++t) acc[t] += bv;
            if (p == 0) qa[c] = acc; else if (p == 1) ka[c] = acc; else va[c] = acc;
        }
    }

#pragma unroll
    for (int c = 0; c < 2; ++c) {
        float s00 = qa[c][0] * ka[c][0], s01 = qa[c][0] * ka[c][1];
        float s10 = qa[c][1] * ka[c][0], s11 = qa[c][1] * ka[c][1];
        float u00 = qa[c][2] * ka[c][2], u01 = qa[c][2] * ka[c][3];
        float u10 = qa[c][3] * ka[c][2], u11 = qa[c][3] * ka[c][3];
#pragma unroll
        for (int mku = 1; mku <= 8; mku <<= 1) {
            s00 += __shfl_xor(s00, mku); s01 += __shfl_xor(s01, mku);
            s10 += __shfl_xor(s10, mku); s11 += __shfl_xor(s11, mku);
            u00 += __shfl_xor(u00, mku); u01 += __shfl_xor(u01, mku);
            u10 += __shfl_xor(u10, mku); u11 += __shfl_xor(u11, mku);
        }
        s00 *= 0.25f; s01 *= 0.25f; s10 *= 0.25f; s11 *= 0.25f;
        u00 *= 0.25f; u01 *= 0.25f; u10 *= 0.25f; u11 *= 0.25f;
        float m0 = fmaxf(s00, s01), m1 = fmaxf(s10, s11);
        float m2 = fmaxf(u00, u01), m3 = fmaxf(u10, u11);
        float e00 = __expf(s00 - m0), e01 = __expf(s01 - m0);
        float e10 = __expf(s10 - m1), e11 = __expf(s11 - m1);
        float f00 = __expf(u00 - m2), f01 = __expf(u01 - m2);
        float f10 = __expf(u10 - m3), f11 = __expf(u11 - m3);
        float i0 = 1.f / (e00 + e01), i1 = 1.f / (e10 + e11);
        float i2 = 1.f / (f00 + f01), i3 = 1.f / (f10 + f11);
        float o0 = (e00 * va[c][0] + e01 * va[c][1]) * i0;
        float o1 = (e10 * va[c][0] + e11 * va[c][1]) * i1;
        float o2 = (f00 * va[c][2] + f01 * va[c][3]) * i2;
        float o3 = (f10 * va[c][2] + f11 * va[c][3]) * i3;
        int ocol = (hg * 2 + c) * 16 + r;
        obf_s[(q * 4 + 0) * 144 + ocol] = f2b(o0);
        obf_s[(q * 4 + 1) * 144 + ocol] = f2b(o1);
        obf_s[(q * 4 + 2) * 144 + ocol] = f2b(o2);
        obf_s[(q * 4 + 3) * 144 + ocol] = f2b(o3);
    }
    __syncthreads();

    bf16x8 ofrag[4];
#pragma unroll
    for (int kc = 0; kc < 4; ++kc)
        ofrag[kc] = *(const bf16x8*)(const void*)(obf_s + r * 144 + q * 8 + kc * 32);
#pragma unroll
    for (int c = 0; c < 2; ++c) {
        int tt = hg * 2 + c;
        f32x4 acc = {0.f, 0.f, 0.f, 0.f};
#pragma unroll
        for (int kc = 0; kc < 4; ++kc) {
            bf16x8 bfrag = *(const bf16x8*)(const void*)(WoutB + (((size_t)tt * 4 + kc) << 9) + lane * 8);
            acc = __builtin_amdgcn_mfma_f32_16x16x32_bf16(ofrag[kc], bfrag, acc, 0, 0, 0);
        }
        int n0 = tt * 16;
        float bv = bout[n0 + r];
        att_s[(q * 2 + 0) * 132 + n0 + r] = 0.5f * (acc[0] + acc[1]) + bv;
        att_s[(q * 2 + 1) * 132 + n0 + r] = 0.5f * (acc[2] + acc[3]) + bv;
    }
    __syncthreads();

    {
        int nl = threadIdx.x >> 5;
        int j2 = threadIdx.x & 31;
        int gnode = b * 8 + nl; if (gnode >= nN) gnode = nN - 1;
        const unsigned short* hrow = hbn + (size_t)gnode * 128 + j2 * 4;
        float x[4]; float s = 0.f, s2 = 0.f;
#pragma unroll
        for (int i = 0; i < 4; ++i) {
            x[i] = att_s[nl * 132 + j2 * 4 + i] + b2f(hrow[i]);
            s += x[i]; s2 += x[i] * x[i];
        }
        s += __shfl_xor(s, 1);  s2 += __shfl_xor(s2, 1);
        s += __shfl_xor(s, 2);  s2 += __shfl_xor(s2, 2);
        s += __shfl_xor(s, 4);  s2 += __shfl_xor(s2, 4);
        s += __shfl_xor(s, 8);  s2 += __shfl_xor(s2, 8);
        s += __shfl_xor(s, 16); s2 += __shfl_xor(s2, 16);
        float mu = s * (1.f / 128.f);
        float var = s2 * (1.f / 128.f) - mu * mu;
        float rstd = rsqrtf(var + EPSV);
        ushort4 o;
        o.x = f2b((x[0] - mu) * rstd * lng[j2 * 4]     + lnb[j2 * 4]);
        o.y = f2b((x[1] - mu) * rstd * lng[j2 * 4 + 1] + lnb[j2 * 4 + 1]);
        o.z = f2b((x[2] - mu) * rstd * lng[j2 * 4 + 2] + lnb[j2 * 4 + 2]);
        o.w = f2b((x[3] - mu) * rstd * lng[j2 * 4 + 3] + lnb[j2 * 4 + 3]);
        *(ushort4*)(hfin + (size_t)gnode * 128 + j2 * 4) = o;
    }
}

// ---------------- classifier stats (F=64) ----------------
__global__ __launch_bounds__(256) void stats64_kernel(const float* __restrict__ z,
                                                      float* __restrict__ sums, int N) {
    __shared__ float ls[4][64], lsq[4][64];
    int f = threadIdx.x & 63, rg = threadIdx.x >> 6;
    int r0 = blockIdx.x * 64 + rg * 16;
    int r1 = r0 + 16; if (r1 > N) r1 = N;
    float s = 0.f, s2 = 0.f;
    for (int r = r0; r < r1; ++r) {
        float v = z[(size_t)r * 64 + f];
        s += v; s2 += v * v;
    }
    ls[rg][f] = s; lsq[rg][f] = s2;
    __syncthreads();
    int t = threadIdx.x;
    if (t < 64) atomicAdd(&sums[t], ls[0][t] + ls[1][t] + ls[2][t] + ls[3][t]);
    else if (t < 128) { int c = t - 64; atomicAdd(&sums[64 + c], lsq[0][c] + lsq[1][c] + lsq[2][c] + lsq[3][c]); }
}

// ---------------- final: BN(inline finalize)+ReLU+Linear(64,10)+log_softmax --
__global__ __launch_bounds__(256) void final_kernel(const float* __restrict__ z,
                                                    const float* __restrict__ sums,
                                                    const float* __restrict__ g,
                                                    const float* __restrict__ be,
                                                    const float* __restrict__ W2,
                                                    const float* __restrict__ b2v,
                                                    float* __restrict__ out, int nN) {
    int node = blockIdx.x * 4 + (threadIdx.x >> 6);
    int lane = threadIdx.x & 63;
    float inv = 1.f / (float)nN;
    float mean = sums[lane] * inv;
    float var = sums[64 + lane] * inv - mean * mean;
    float sc = g[lane] * rsqrtf(var + EPSV);
    float sh = be[lane] - mean * sc;
    float v = 0.f;
    if (node < nN) v = fmaxf(z[(size_t)node * 64 + lane] * sc + sh, 0.f);
    float p[10];
    const float* wrow = W2 + lane * 10;
#pragma unroll
    for (int c = 0; c < 10; ++c) p[c] = v * wrow[c];
#pragma unroll
    for (int off = 32; off >= 1; off >>= 1) {
#pragma unroll
        for (int c = 0; c < 10; ++c) p[c] += __shfl_xor(p[c], off);
    }
    if (node >= nN) return;
    float l[10], mx = -1e30f;
#pragma unroll
    for (int c = 0; c < 10; ++c) { l[c] = p[c] + b2v[c]; mx = fmaxf(mx, l[c]); }
    float se = 0.f;
#pragma unroll
    for (int c = 0; c < 10; ++c) se += expf(l[c] - mx);
    float lse = mx + logf(se);
    if (lane < 10) out[(size_t)node * 10 + lane] = l[lane] - lse;
}

// ---------------------------------------------------------------------------
static inline int cdiv(long a, long b) { return (int)((a + b - 1) / b); }

extern "C" void kernel_launch(void* const* d_in, const int* in_sizes, int n_in,
                              void* d_out, int out_size, void* d_ws, size_t ws_size,
                              hipStream_t stream) {
    const float* node_feat = (const float*)d_in[0];
    const int*   nedge     = (const int*)d_in[1];
    const float* comm_feat = (const float*)d_in[2];
    const int*   cedge     = (const int*)d_in[3];
    const int*   n2c       = (const int*)d_in[4];
    const float* node_W    = (const float*)d_in[5];
    const float* node_b    = (const float*)d_in[6];
    const float* node_g    = (const float*)d_in[7];
    const float* node_beta = (const float*)d_in[8];
    const float* comm_W    = (const float*)d_in[9];
    const float* comm_b    = (const float*)d_in[10];
    const float* comm_g    = (const float*)d_in[11];
    const float* comm_beta = (const float*)d_in[12];
    const float* attn_in_w = (const float*)d_in[13];
    const float* attn_in_b = (const float*)d_in[14];
    const float* attn_out_w= (const float*)d_in[15];
    const float* attn_out_b= (const float*)d_in[16];
    const float* ln_g      = (const float*)d_in[17];
    const float* ln_b      = (const float*)d_in[18];
    const float* cls_W1    = (const float*)d_in[19];
    const float* cls_b1    = (const float*)d_in[20];
    const float* cls_bn_g  = (const float*)d_in[21];
    const float* cls_bn_b  = (const float*)d_in[22];
    const float* cls_W2    = (const float*)d_in[23];
    const float* cls_b2    = (const float*)d_in[24];

    const int nN = in_sizes[0] / 128;
    const int nE = in_sizes[1] / 2;
    const int nC = in_sizes[2] / 128;
    const int cE = in_sizes[3] / 2;
    const int padE_n = nE + 8 * nN;
    const int padE_c = cE + 8 * nC;

    char* ws = (char*)d_ws;
    size_t off = 0;
    auto alloc = [&](size_t bytes) -> char* {
        char* p = ws + off;
        off = (off + bytes + 255) & ~(size_t)255;
        return p;
    };
    // ---- contiguous zero region (single memset) ----
    size_t zero_begin = off;
    int*   cnt_n  = (int*)alloc((size_t)nN * 4);
    int*   cur_n  = (int*)alloc((size_t)nN * 4);
    int*   cnt_c  = (int*)alloc((size_t)nC * 4);
    int*   cur_c  = (int*)alloc((size_t)nC * 4);
    float* gsums  = (float*)alloc((size_t)6 * 256 * 4);
    float* csums  = (float*)alloc(128 * 4);
    int2*  ew_n   = (int2*)alloc((size_t)padE_n * 8);  // pad slots stay (0,0)
    int2*  ew_c   = (int2*)alloc((size_t)padE_c * 8);
    size_t zero_bytes = off - zero_begin;
    // ---- CSR aux ----
    int*   rs_n   = (int*)alloc((size_t)(nN + 1) * 4);
    int*   bsum_n = (int*)alloc(256 * 4);
    float* dinv_n = (float*)alloc((size_t)nN * 4);
    int*   rs_c   = (int*)alloc((size_t)(nC + 1) * 4);
    int*   bsum_c = (int*)alloc(256 * 4);
    float* dinv_c = (float*)alloc((size_t)nC * 4);
    // ---- activations / weights ----
    unsigned short* hb_n  = (unsigned short*)alloc((size_t)nN * 256);
    unsigned short* hb_c  = (unsigned short*)alloc((size_t)nC * 256);
    unsigned short* cfb   = (unsigned short*)alloc((size_t)nC * 256);
    unsigned short* m_cb  = (unsigned short*)alloc((size_t)nC * 256);
    float*          agg_c = (float*)alloc((size_t)nC * 512);
    unsigned short* WtN  = (unsigned short*)alloc((size_t)3 * 16384 * 2);
    unsigned short* WtC  = (unsigned short*)alloc((size_t)3 * 16384 * 2);
    unsigned short* W1t  = (unsigned short*)alloc((size_t)64 * 128 * 2);
    unsigned short* WinB = (unsigned short*)alloc((size_t)384 * 128 * 2);
    unsigned short* WoutB= (unsigned short*)alloc((size_t)128 * 128 * 2);
    unsigned short* m_nb = (unsigned short*)alloc((size_t)nN * 256);
    float*          agg_n= (float*)alloc((size_t)nN * 512);
    // aliases (disjoint liveness)
    unsigned short* nfb  = (unsigned short*)agg_n;
    unsigned short* hfin = m_nb;
    float*          z    = agg_n;

    hipMemsetAsync(ws + zero_begin, 0, zero_bytes, stream);

    // ---- prep ----
    long prepN = 49152L * 3 + 8192 + 16384 + (long)nC * 128 + (long)nN * 128;
    prep_kernel<<<cdiv(prepN, 256), 256, 0, stream>>>(
        node_W, comm_W, cls_W1, attn_in_w, attn_out_w, comm_feat, node_feat,
        WtN, WtC, W1t, WinB, WoutB, cfb, nfb, nC * 128, nN * 128);

    // ---- CSR build (rows padded to x8) ----
    count_dual<<<cdiv((long)nE + cE, 256), 256, 0, stream>>>(nedge + nE, cnt_n, nE, cedge + cE, cnt_c, cE);
    dinv_dual<<<cdiv((long)nN + nC, 256), 256, 0, stream>>>(cnt_n, dinv_n, nN, cnt_c, dinv_c, nC);
    int nbN = cdiv(nN, 1024), nbC = cdiv(nC, 1024);
    scan_block_dual<<<nbN + nbC, 1024, 0, stream>>>(cnt_n, rs_n, bsum_n, nN, nbN, cnt_c, rs_c, bsum_c, nC);
    scan_sums_dual<<<1, 64, 0, stream>>>(bsum_n, nbN, bsum_c, nbC);
    scan_add_dual<<<cdiv((long)nN + nC, 256), 256, 0, stream>>>(rs_n, bsum_n, nN, rs_c, bsum_c, nC);
    fill_dual<<<cdiv((long)nE + cE, 256), 256, 0, stream>>>(
        nedge, nedge + nE, dinv_n, rs_n, cur_n, ew_n, nE,
        cedge, cedge + cE, dinv_c, rs_c, cur_c, ew_c, cE);

    // ---- GCN layers ----
    int gemmA = cdiv(nN, 64), gemmB = cdiv(nC, 64);
    int gatA = cdiv(nN, 4), gatB = cdiv(nC, 4);
    int appA = cdiv((long)nN * 128, 1024), appB = cdiv((long)nC * 128, 1024);
    for (int i = 0; i < 3; ++i) {
        const unsigned short* A0 = i == 0 ? nfb : hb_n;
        const unsigned short* A1 = i == 0 ? cfb : hb_c;
        float* s0 = gsums + (size_t)(i * 2 + 0) * 256;
        float* s1 = gsums + (size_t)(i * 2 + 1) * 256;
        gemm_dual<<<gemmA + gemmB, 256, 0, stream>>>(
            A0, WtN + i * 16384, m_nb, nN, gemmA,
            A1, WtC + i * 16384, m_cb, nC);
        gather_dual<<<gatA + gatB, 256, 0, stream>>>(
            m_nb, rs_n, cnt_n, ew_n, dinv_n, node_b + i * 128, agg_n, nN, gatA,
            m_cb, rs_c, cnt_c, ew_c, dinv_c, comm_b + i * 128, agg_c, nC);
        stats_dual<<<256 + 4, 256, 0, stream>>>(agg_n, s0, nN, 256, agg_c, s1, nC);
        apply_dual<<<appA + appB, 256, 0, stream>>>(
            agg_n, s0, node_g + i * 128, node_beta + i * 128, hb_n, nN, appA, i > 0 ? 1 : 0,
            agg_c, s1, comm_g + i * 128, comm_beta + i * 128, hb_c, nC);
    }

    // ---- fused MHA + mean + residual + LN ----
    mha_fused_kernel<<<cdiv(nN, 8), 256, 0, stream>>>(
        hb_n, hb_c, n2c, WinB, attn_in_b, WoutB, attn_out_b, ln_g, ln_b, hfin, nN, nC);

    // ---- classifier ----
    int waves1 = (nN + 15) / 16;
    gemm_kernel<<<cdiv((long)waves1 * 64, 256), 256, 0, stream>>>(
        hfin, W1t, cls_b1, z, nN, 64);
    stats64_kernel<<<cdiv(nN, 64), 256, 0, stream>>>(z, csums, nN);
    final_kernel<<<cdiv(nN, 4), 256, 0, stream>>>(z, csums, cls_bn_g, cls_bn_b,
                                                  cls_W2, cls_b2, (float*)d_out, nN);
}

// Round 14
// 544.405 us; speedup vs baseline: 1.1957x; 1.0173x over previous
//
#include <hip/hip_runtime.h>
#include <hip/hip_bf16.h>
#include <cstdint>
#include <cstddef>

// ---------------------------------------------------------------------------
// ImprovedCrossScaleGNN on MI355X (gfx950).
// Inputs float32 + int32, output float32. bf16 MFMA GEMMs, f32 stats.
// R13->R14: (1) revert gather/fill to R11 form (int2 pack was -15us).
// (2) M-BLOCKING x2 in mha + gemm: each wave owns two 16-row A tiles and
// reuses every B fragment for two MFMAs -> halves the dominant redundant
// B-weight L2 traffic (mha read ~600 MB of Win/Wout per dispatch).
// ---------------------------------------------------------------------------

typedef __attribute__((ext_vector_type(8))) short bf16x8;
typedef __attribute__((ext_vector_type(4))) float f32x4;

#define EPSV 1e-5f

__device__ __forceinline__ float b2f(unsigned short u) {
    union { unsigned int i; float f; } x; x.i = ((unsigned int)u) << 16; return x.f;
}
__device__ __forceinline__ unsigned short f2b(float f) {
    union { float f; unsigned int i; } x; x.f = f;
    unsigned int i = x.i;
    return (unsigned short)((i + 0x7fffu + ((i >> 16) & 1u)) >> 16);
}

// ---------------- prep: weights -> fragment-linear bf16 + feature casts ------
__global__ void prep_kernel(const float* __restrict__ node_W, const float* __restrict__ comm_W,
                            const float* __restrict__ cls_W1, const float* __restrict__ attn_in_w,
                            const float* __restrict__ attn_out_w, const float* __restrict__ comm_feat,
                            const float* __restrict__ node_feat,
                            unsigned short* __restrict__ WtN, unsigned short* __restrict__ WtC,
                            unsigned short* __restrict__ W1t, unsigned short* __restrict__ WinB,
                            unsigned short* __restrict__ WoutB, unsigned short* __restrict__ cfb,
                            unsigned short* __restrict__ nfb, int nC128, int nN128) {
    int idx = blockIdx.x * 256 + threadIdx.x;
    if (idx < 49152) {
        int l = idx >> 14, e = idx & 16383;
        int j = e & 7, lane = (e >> 3) & 63, kc = (e >> 9) & 3, t = e >> 11;
        int col = t * 16 + (lane & 15);
        int k = (lane >> 4) * 8 + kc * 32 + j;
        WtN[idx] = f2b(node_W[l * 16384 + k * 128 + col]); return;
    }
    idx -= 49152;
    if (idx < 49152) {
        int l = idx >> 14, e = idx & 16383;
        int j = e & 7, lane = (e >> 3) & 63, kc = (e >> 9) & 3, t = e >> 11;
        int col = t * 16 + (lane & 15);
        int k = (lane >> 4) * 8 + kc * 32 + j;
        WtC[idx] = f2b(comm_W[l * 16384 + k * 128 + col]); return;
    }
    idx -= 49152;
    if (idx < 8192) {
        int e = idx;
        int j = e & 7, lane = (e >> 3) & 63, kc = (e >> 9) & 3, t = e >> 11;
        int col = t * 16 + (lane & 15);
        int k = (lane >> 4) * 8 + kc * 32 + j;
        W1t[idx] = f2b(cls_W1[k * 64 + col]); return;
    }
    idx -= 8192;
    if (idx < 49152) {
        int e = idx;
        int j = e & 7, lane = (e >> 3) & 63, kc = (e >> 9) & 3, t = e >> 11;
        int col = t * 16 + (lane & 15);
        int k = (lane >> 4) * 8 + kc * 32 + j;
        WinB[idx] = f2b(attn_in_w[col * 128 + k]); return;
    }
    idx -= 49152;
    if (idx < 16384) {
        int e = idx;
        int j = e & 7, lane = (e >> 3) & 63, kc = (e >> 9) & 3, t = e >> 11;
        int col = t * 16 + (lane & 15);
        int k = (lane >> 4) * 8 + kc * 32 + j;
        WoutB[idx] = f2b(attn_out_w[col * 128 + k]); return;
    }
    idx -= 16384;
    if (idx < nC128) { cfb[idx] = f2b(comm_feat[idx]); return; }
    idx -= nC128;
    if (idx < nN128) { nfb[idx] = f2b(node_feat[idx]); }
}

// ---------------- CSR build (dual) ----------------
__global__ void count_dual(const int* __restrict__ nd, int* __restrict__ cnt_n, int nE,
                           const int* __restrict__ cd, int* __restrict__ cnt_c, int cE) {
    int t = blockIdx.x * 256 + threadIdx.x;
    if (t < nE) atomicAdd(&cnt_n[nd[t]], 1);
    else if (t - nE < cE) atomicAdd(&cnt_c[cd[t - nE]], 1);
}

__global__ void dinv_dual(const int* __restrict__ cnt_n, float* __restrict__ di_n, int nN,
                          const int* __restrict__ cnt_c, float* __restrict__ di_c, int nC) {
    int t = blockIdx.x * 256 + threadIdx.x;
    if (t < nN) di_n[t] = rsqrtf((float)cnt_n[t] + 1.0f);
    else if (t - nN < nC) di_c[t - nN] = rsqrtf((float)cnt_c[t - nN] + 1.0f);
}

// scans PADDED counts: ceil8(cnt)
__global__ void scan_block_dual(const int* __restrict__ cnt_n, int* __restrict__ rs_n,
                                int* __restrict__ bsum_n, int nN, int nbN,
                                const int* __restrict__ cnt_c, int* __restrict__ rs_c,
                                int* __restrict__ bsum_c, int nC) {
    __shared__ int tmp[2048];
    const int* cnt; int* excl; int* bsum; int n, lb;
    if ((int)blockIdx.x < nbN) { cnt = cnt_n; excl = rs_n; bsum = bsum_n; n = nN; lb = blockIdx.x; }
    else { cnt = cnt_c; excl = rs_c; bsum = bsum_c; n = nC; lb = blockIdx.x - nbN; }
    int tid = threadIdx.x;
    int gid = lb * 1024 + tid;
    int v = (gid < n) ? ((cnt[gid] + 7) & ~7) : 0;
    int buf = 0;
    tmp[tid] = v;
    __syncthreads();
    for (int d = 1; d < 1024; d <<= 1) {
        int t = tmp[buf * 1024 + tid];
        int add = (tid >= d) ? tmp[buf * 1024 + tid - d] : 0;
        tmp[(1 - buf) * 1024 + tid] = t + add;
        buf = 1 - buf;
        __syncthreads();
    }
    int inc = tmp[buf * 1024 + tid];
    if (gid < n) excl[gid] = inc - v;
    if (tid == 1023) bsum[lb] = inc;
}

__global__ void scan_sums_dual(int* __restrict__ bsum_n, int nbN,
                               int* __restrict__ bsum_c, int nbC) {
    if (threadIdx.x == 0) {
        int acc = 0;
        for (int i = 0; i < nbN; ++i) { int t = bsum_n[i]; bsum_n[i] = acc; acc += t; }
    } else if (threadIdx.x == 1) {
        int acc = 0;
        for (int i = 0; i < nbC; ++i) { int t = bsum_c[i]; bsum_c[i] = acc; acc += t; }
    }
}

__global__ void scan_add_dual(int* __restrict__ rs_n, const int* __restrict__ bsum_n, int nN,
                              int* __restrict__ rs_c, const int* __restrict__ bsum_c, int nC) {
    int gid = blockIdx.x * 256 + threadIdx.x;
    if (gid < nN) rs_n[gid] += bsum_n[gid >> 10];
    else {
        int g = gid - nN;
        if (g < nC) rs_c[g] += bsum_c[g >> 10];
    }
}

__global__ void fill_dual(const int* __restrict__ ns, const int* __restrict__ ndst,
                          const float* __restrict__ di_n, const int* __restrict__ rs_n,
                          int* __restrict__ cur_n, int* __restrict__ csrc_n,
                          float* __restrict__ cw_n, int nE,
                          const int* __restrict__ cs, const int* __restrict__ cdst,
                          const float* __restrict__ di_c, const int* __restrict__ rs_c,
                          int* __restrict__ cur_c, int* __restrict__ csrc_c,
                          float* __restrict__ cw_c, int cE) {
    int e = blockIdx.x * 256 + threadIdx.x;
    if (e < nE) {
        int s = ns[e], d = ndst[e];
        int pos = atomicAdd(&cur_n[d], 1);
        int slot = rs_n[d] + pos;
        csrc_n[slot] = s;
        cw_n[slot] = di_n[s] * di_n[d];
    } else if (e - nE < cE) {
        int ee = e - nE;
        int s = cs[ee], d = cdst[ee];
        int pos = atomicAdd(&cur_c[d], 1);
        int slot = rs_c[d] + pos;
        csrc_c[slot] = s;
        cw_c[slot] = di_c[s] * di_c[d];
    }
}

// ---------------- MFMA GEMM wave body: 32 rows x 128 cols, bf16 out ----------
// Two 16-row A tiles per wave; each B fragment loaded once, used twice.
__device__ __forceinline__ void gemm_wave_128x2(const unsigned short* __restrict__ A,
                                                const unsigned short* __restrict__ Bt,
                                                unsigned short* __restrict__ D,
                                                int M, int m0, int lane) {
    int r = lane & 15, q = lane >> 4;
    int ar0 = m0 + r;       if (ar0 >= M) ar0 = M - 1;
    int ar1 = m0 + 16 + r;  if (ar1 >= M) ar1 = M - 1;
    const unsigned short* ap0 = A + (size_t)ar0 * 128 + q * 8;
    const unsigned short* ap1 = A + (size_t)ar1 * 128 + q * 8;
    bf16x8 afrag0[4], afrag1[4];
#pragma unroll
    for (int kc = 0; kc < 4; ++kc) {
        afrag0[kc] = *(const bf16x8*)(const void*)(ap0 + kc * 32);
        afrag1[kc] = *(const bf16x8*)(const void*)(ap1 + kc * 32);
    }
#pragma unroll
    for (int tt = 0; tt < 8; ++tt) {
        f32x4 acc0 = {0.f, 0.f, 0.f, 0.f};
        f32x4 acc1 = {0.f, 0.f, 0.f, 0.f};
#pragma unroll
        for (int kc = 0; kc < 4; ++kc) {
            bf16x8 bfrag = *(const bf16x8*)(const void*)(Bt + (((size_t)tt * 4 + kc) << 9) + lane * 8);
            acc0 = __builtin_amdgcn_mfma_f32_16x16x32_bf16(afrag0[kc], bfrag, acc0, 0, 0, 0);
            acc1 = __builtin_amdgcn_mfma_f32_16x16x32_bf16(afrag1[kc], bfrag, acc1, 0, 0, 0);
        }
        int n0 = tt * 16;
#pragma unroll
        for (int t = 0; t < 4; ++t) {
            int row0 = m0 + q * 4 + t;
            int row1 = row0 + 16;
            if (row0 < M) D[(size_t)row0 * 128 + n0 + r] = f2b(acc0[t]);
            if (row1 < M) D[(size_t)row1 * 128 + n0 + r] = f2b(acc1[t]);
        }
    }
}

__global__ __launch_bounds__(256) void gemm_dual(
    const unsigned short* __restrict__ A0, const unsigned short* __restrict__ Bt0,
    unsigned short* __restrict__ D0, int M0, int blocksA,
    const unsigned short* __restrict__ A1, const unsigned short* __restrict__ Bt1,
    unsigned short* __restrict__ D1, int M1) {
    int blk = blockIdx.x;
    const unsigned short *A, *Bt; unsigned short* D; int M, lb;
    if (blk < blocksA) { A = A0; Bt = Bt0; D = D0; M = M0; lb = blk; }
    else { A = A1; Bt = Bt1; D = D1; M = M1; lb = blk - blocksA; }
    int m0 = (lb * 4 + (int)(threadIdx.x >> 6)) * 32;
    if (m0 >= M) return;
    gemm_wave_128x2(A, Bt, D, M, m0, threadIdx.x & 63);
}

// classifier GEMM (generic Ncol, f32 out, bias); Bt fragment-linear
__global__ void gemm_kernel(const unsigned short* __restrict__ A,
                            const unsigned short* __restrict__ Bt,
                            const float* __restrict__ bias,
                            float* __restrict__ D, int M, int Ncol) {
    int wave = (blockIdx.x * blockDim.x + threadIdx.x) >> 6;
    int lane = threadIdx.x & 63;
    int m0 = wave * 16;
    if (m0 >= M) return;
    int r = lane & 15, q = lane >> 4;
    int arow = m0 + r; if (arow >= M) arow = M - 1;
    const unsigned short* ap = A + (size_t)arow * 128 + q * 8;
    bf16x8 afrag[4];
#pragma unroll
    for (int kc = 0; kc < 4; ++kc)
        afrag[kc] = *(const bf16x8*)(const void*)(ap + kc * 32);
    int ntiles = Ncol >> 4;
    for (int tt = 0; tt < ntiles; ++tt) {
        f32x4 acc = {0.f, 0.f, 0.f, 0.f};
#pragma unroll
        for (int kc = 0; kc < 4; ++kc) {
            bf16x8 bfrag = *(const bf16x8*)(const void*)(Bt + (((size_t)tt * 4 + kc) << 9) + lane * 8);
            acc = __builtin_amdgcn_mfma_f32_16x16x32_bf16(afrag[kc], bfrag, acc, 0, 0, 0);
        }
        int n0 = tt * 16;
        float bv = bias[n0 + r];
#pragma unroll
        for (int t = 0; t < 4; ++t) {
            int row = m0 + q * 4 + t;
            if (row < M) D[(size_t)row * Ncol + n0 + r] = acc[t] + bv;
        }
    }
}

// ---------------- gather (CSR, rows padded x8), dual-branch (R11 form) -------
__global__ __launch_bounds__(256) void gather_dual(
    const unsigned short* __restrict__ m0, const int* __restrict__ rs0,
    const int* __restrict__ cnt0,
    const int* __restrict__ cs0, const float* __restrict__ cw0,
    const float* __restrict__ di0, const float* __restrict__ b0,
    float* __restrict__ agg0, int n0, int blocksA,
    const unsigned short* __restrict__ m1, const int* __restrict__ rs1,
    const int* __restrict__ cnt1,
    const int* __restrict__ cs1, const float* __restrict__ cw1,
    const float* __restrict__ di1, const float* __restrict__ b1,
    float* __restrict__ agg1, int n1) {
    int blk = blockIdx.x;
    const unsigned short* m; const int *rs, *cnt, *cs; const float *cw, *di, *bias;
    float *agg; int n, lb;
    if (blk < blocksA) { m = m0; rs = rs0; cnt = cnt0; cs = cs0; cw = cw0; di = di0; bias = b0; agg = agg0; n = n0; lb = blk; }
    else { m = m1; rs = rs1; cnt = cnt1; cs = cs1; cw = cw1; di = di1; bias = b1; agg = agg1; n = n1; lb = blk - blocksA; }
    int wib = threadIdx.x >> 6, lane = threadIdx.x & 63;
    int node = lb * 4 + wib;
    if (node >= n) return;
    int start = rs[node];
    int end = start + ((cnt[node] + 7) & ~7);
    float a0 = 0.f, a1 = 0.f;
    for (int i = start; i < end; i += 8) {
        int s[8]; float w[8]; unsigned int v[8];
#pragma unroll
        for (int j = 0; j < 8; ++j) { s[j] = cs[i + j]; w[j] = cw[i + j]; }
#pragma unroll
        for (int j = 0; j < 8; ++j)
            v[j] = *(const unsigned int*)(m + (size_t)s[j] * 128 + 2 * lane);
#pragma unroll
        for (int j = 0; j < 8; ++j) {
            a0 += b2f((unsigned short)(v[j] & 0xffff)) * w[j];
            a1 += b2f((unsigned short)(v[j] >> 16)) * w[j];
        }
    }
    float d = di[node]; float wself = d * d;
    unsigned int v = *(const unsigned int*)(m + (size_t)node * 128 + 2 * lane);
    a0 += b2f((unsigned short)(v & 0xffff)) * wself + bias[2 * lane];
    a1 += b2f((unsigned short)(v >> 16)) * wself + bias[2 * lane + 1];
    float2 o; o.x = a0; o.y = a1;
    ((float2*)(agg + (size_t)node * 128))[lane] = o;
}

// ---------------- BN stats (streaming pass over agg), dual-branch ------------
__global__ __launch_bounds__(256) void stats_dual(
    const float* __restrict__ agg0, float* __restrict__ sums0, int n0, int blocksA,
    const float* __restrict__ agg1, float* __restrict__ sums1, int n1) {
    __shared__ float rsum[256], rsq[256];
    int blk = blockIdx.x;
    const float* agg; float* sums; int n, lb, nb;
    if (blk < blocksA) { agg = agg0; sums = sums0; n = n0; lb = blk; nb = blocksA; }
    else { agg = agg1; sums = sums1; n = n1; lb = blk - blocksA; nb = gridDim.x - blocksA; }
    int rpb = (n + nb - 1) / nb;
    int t = threadIdx.x;
    int f = t & 127, half = t >> 7;
    int r0 = lb * rpb, r1 = r0 + rpb; if (r1 > n) r1 = n;
    float s = 0.f, s2 = 0.f;
    for (int r = r0 + half; r < r1; r += 2) {
        float v = agg[(size_t)r * 128 + f];
        s += v; s2 += v * v;
    }
    rsum[t] = s; rsq[t] = s2;
    __syncthreads();
    if (t < 128) atomicAdd(&sums[t], rsum[t] + rsum[t + 128]);
    else atomicAdd(&sums[128 + f], rsq[f] + rsq[t]);
}

// ---------------- BN finalize+apply, dual-branch -----------------------------
__global__ __launch_bounds__(256) void apply_dual(
    const float* __restrict__ agg0, const float* __restrict__ sums0,
    const float* __restrict__ g0, const float* __restrict__ be0,
    unsigned short* __restrict__ hb0, int n0, int blocksA, int useRes,
    const float* __restrict__ agg1, const float* __restrict__ sums1,
    const float* __restrict__ g1, const float* __restrict__ be1,
    unsigned short* __restrict__ hb1, int n1) {
    __shared__ float sc[128], sh[128];
    int blk = blockIdx.x;
    const float *agg, *sums, *g, *be; unsigned short* hb; int n, lb;
    if (blk < blocksA) { agg = agg0; sums = sums0; g = g0; be = be0; hb = hb0; n = n0; lb = blk; }
    else { agg = agg1; sums = sums1; g = g1; be = be1; hb = hb1; n = n1; lb = blk - blocksA; }
    int t = threadIdx.x;
    if (t < 128) {
        float inv = 1.f / (float)n;
        float mean = sums[t] * inv;
        float var = sums[128 + t] * inv - mean * mean;
        float rstd = rsqrtf(var + EPSV);
        float s = g[t] * rstd;
        sc[t] = s;
        sh[t] = be[t] - mean * s;
    }
    __syncthreads();
    int base = lb * 1024 + t * 4;
    if (base < n * 128) {
        float4 a = *(const float4*)(agg + base);
        ushort4 h = *(const ushort4*)(hb + base);
        int f = base & 127;
        float v0 = fmaxf(a.x * sc[f] + sh[f], 0.f);
        float v1 = fmaxf(a.y * sc[f + 1] + sh[f + 1], 0.f);
        float v2 = fmaxf(a.z * sc[f + 2] + sh[f + 2], 0.f);
        float v3 = fmaxf(a.w * sc[f + 3] + sh[f + 3], 0.f);
        if (useRes) { v0 += b2f(h.x); v1 += b2f(h.y); v2 += b2f(h.z); v3 += b2f(h.w); }
        ushort4 o; o.x = f2b(v0); o.y = f2b(v1); o.z = f2b(v2); o.w = f2b(v3);
        *(ushort4*)(hb + base) = o;
    }
}

// ---------------- fused MHA + mean + residual + LayerNorm --------------------
// Block = 16 nodes (32 seq rows) = 2 row-groups; 4 waves, wave hg owns head
// group hg for BOTH row-groups (B frags loaded once, used twice).
__global__ __launch_bounds__(256) void mha_fused_kernel(
    const unsigned short* __restrict__ hbn, const unsigned short* __restrict__ hbc,
    const int* __restrict__ map,
    const unsigned short* __restrict__ WinB, const float* __restrict__ bin,
    const unsigned short* __restrict__ WoutB, const float* __restrict__ bout,
    const float* __restrict__ lng, const float* __restrict__ lnb,
    unsigned short* __restrict__ hfin, int nN, int nC) {
    __shared__ unsigned short obf_s[2][16 * 144];
    __shared__ float att_s[2][8 * 132];

    int b = blockIdx.x;
    int hg = threadIdx.x >> 6;
    int lane = threadIdx.x & 63;
    int r = lane & 15, q = lane >> 4;

    // A fragments for both row-groups
    bf16x8 afrag[2][4];
#pragma unroll
    for (int g = 0; g < 2; ++g) {
        int anode = b * 16 + g * 8 + (r >> 1);
        if (anode >= nN) anode = nN - 1;
        const unsigned short* arow;
        if (r & 1) {
            int c = map[anode]; c = c < 0 ? 0 : (c >= nC ? nC - 1 : c);
            arow = hbc + (size_t)c * 128;
        } else {
            arow = hbn + (size_t)anode * 128;
        }
#pragma unroll
        for (int kc = 0; kc < 4; ++kc)
            afrag[g][kc] = *(const bf16x8*)(const void*)(arow + q * 8 + kc * 32);
    }

    // ---- phase A: q/k/v for this wave's 2 heads x 2 row-groups, in regs ----
    f32x4 qa[2][2], ka[2][2], va[2][2];   // [group][head-in-group]
#pragma unroll
    for (int p = 0; p < 3; ++p) {
#pragma unroll
        for (int c = 0; c < 2; ++c) {
            int tt = p * 8 + hg * 2 + c;
            f32x4 acc0 = {0.f, 0.f, 0.f, 0.f};
            f32x4 acc1 = {0.f, 0.f, 0.f, 0.f};
#pragma unroll
            for (int kc = 0; kc < 4; ++kc) {
                bf16x8 bfrag = *(const bf16x8*)(const void*)(WinB + (((size_t)tt * 4 + kc) << 9) + lane * 8);
                acc0 = __builtin_amdgcn_mfma_f32_16x16x32_bf16(afrag[0][kc], bfrag, acc0, 0, 0, 0);
                acc1 = __builtin_amdgcn_mfma_f32_16x16x32_bf16(afrag[1][kc], bfrag, acc1, 0, 0, 0);
            }
            float bv = bin[tt * 16 + r];
#pragma unroll
            for (int t = 0; t < 4; ++t) { acc0[t] += bv; acc1[t] += bv; }
            if (p == 0)      { qa[0][c] = acc0; qa[1][c] = acc1; }
            else if (p == 1) { ka[0][c] = acc0; ka[1][c] = acc1; }
            else             { va[0][c] = acc0; va[1][c] = acc1; }
        }
    }

    // ---- phase B: in-register attention per group x head ----
#pragma unroll
    for (int g = 0; g < 2; ++g) {
#pragma unroll
        for (int c = 0; c < 2; ++c) {
            float s00 = qa[g][c][0] * ka[g][c][0], s01 = qa[g][c][0] * ka[g][c][1];
            float s10 = qa[g][c][1] * ka[g][c][0], s11 = qa[g][c][1] * ka[g][c][1];
            float u00 = qa[g][c][2] * ka[g][c][2], u01 = qa[g][c][2] * ka[g][c][3];
            float u10 = qa[g][c][3] * ka[g][c][2], u11 = qa[g][c][3] * ka[g][c][3];
#pragma unroll
            for (int mku = 1; mku <= 8; mku <<= 1) {
                s00 += __shfl_xor(s00, mku); s01 += __shfl_xor(s01, mku);
                s10 += __shfl_xor(s10, mku); s11 += __shfl_xor(s11, mku);
                u00 += __shfl_xor(u00, mku); u01 += __shfl_xor(u01, mku);
                u10 += __shfl_xor(u10, mku); u11 += __shfl_xor(u11, mku);
            }
            s00 *= 0.25f; s01 *= 0.25f; s10 *= 0.25f; s11 *= 0.25f;
            u00 *= 0.25f; u01 *= 0.25f; u10 *= 0.25f; u11 *= 0.25f;
            float m0 = fmaxf(s00, s01), m1 = fmaxf(s10, s11);
            float m2 = fmaxf(u00, u01), m3 = fmaxf(u10, u11);
            float e00 = __expf(s00 - m0), e01 = __expf(s01 - m0);
            float e10 = __expf(s10 - m1), e11 = __expf(s11 - m1);
            float f00 = __expf(u00 - m2), f01 = __expf(u01 - m2);
            float f10 = __expf(u10 - m3), f11 = __expf(u11 - m3);
            float i0 = 1.f / (e00 + e01), i1 = 1.f / (e10 + e11);
            float i2 = 1.f / (f00 + f01), i3 = 1.f / (f10 + f11);
            float o0 = (e00 * va[g][c][0] + e01 * va[g][c][1]) * i0;
            float o1 = (e10 * va[g][c][0] + e11 * va[g][c][1]) * i1;
            float o2 = (f00 * va[g][c][2] + f01 * va[g][c][3]) * i2;
            float o3 = (f10 * va[g][c][2] + f11 * va[g][c][3]) * i3;
            int ocol = (hg * 2 + c) * 16 + r;
            obf_s[g][(q * 4 + 0) * 144 + ocol] = f2b(o0);
            obf_s[g][(q * 4 + 1) * 144 + ocol] = f2b(o1);
            obf_s[g][(q * 4 + 2) * 144 + ocol] = f2b(o2);
            obf_s[g][(q * 4 + 3) * 144 + ocol] = f2b(o3);
        }
    }
    __syncthreads();

    // ---- phase C: out-proj; wave hg handles tiles {2hg, 2hg+1} for both groups
    bf16x8 ofrag[2][4];
#pragma unroll
    for (int g = 0; g < 2; ++g)
#pragma unroll
        for (int kc = 0; kc < 4; ++kc)
            ofrag[g][kc] = *(const bf16x8*)(const void*)(obf_s[g] + r * 144 + q * 8 + kc * 32);
#pragma unroll
    for (int c = 0; c < 2; ++c) {
        int tt = hg * 2 + c;
        f32x4 acc0 = {0.f, 0.f, 0.f, 0.f};
        f32x4 acc1 = {0.f, 0.f, 0.f, 0.f};
#pragma unroll
        for (int kc = 0; kc < 4; ++kc) {
            bf16x8 bfrag = *(const bf16x8*)(const void*)(WoutB + (((size_t)tt * 4 + kc) << 9) + lane * 8);
            acc0 = __builtin_amdgcn_mfma_f32_16x16x32_bf16(ofrag[0][kc], bfrag, acc0, 0, 0, 0);
            acc1 = __builtin_amdgcn_mfma_f32_16x16x32_bf16(ofrag[1][kc], bfrag, acc1, 0, 0, 0);
        }
        int n0 = tt * 16;
        float bv = bout[n0 + r];
        att_s[0][(q * 2 + 0) * 132 + n0 + r] = 0.5f * (acc0[0] + acc0[1]) + bv;
        att_s[0][(q * 2 + 1) * 132 + n0 + r] = 0.5f * (acc0[2] + acc0[3]) + bv;
        att_s[1][(q * 2 + 0) * 132 + n0 + r] = 0.5f * (acc1[0] + acc1[1]) + bv;
        att_s[1][(q * 2 + 1) * 132 + n0 + r] = 0.5f * (acc1[2] + acc1[3]) + bv;
    }
    __syncthreads();

    // ---- phase D: residual + LayerNorm (16 lanes per node, 8 cols each) ----
    {
        int nl = threadIdx.x >> 4;       // node local 0..15
        int j = threadIdx.x & 15;        // col group (8 cols)
        int g = nl >> 3, rg = nl & 7;
        int gnode = b * 16 + nl; if (gnode >= nN) gnode = nN - 1;
        const unsigned short* hrow = hbn + (size_t)gnode * 128 + j * 8;
        float x[8]; float s = 0.f, s2 = 0.f;
#pragma unroll
        for (int i = 0; i < 8; ++i) {
            x[i] = att_s[g][rg * 132 + j * 8 + i] + b2f(hrow[i]);
            s += x[i]; s2 += x[i] * x[i];
        }
        s += __shfl_xor(s, 1);  s2 += __shfl_xor(s2, 1);
        s += __shfl_xor(s, 2);  s2 += __shfl_xor(s2, 2);
        s += __shfl_xor(s, 4);  s2 += __shfl_xor(s2, 4);
        s += __shfl_xor(s, 8);  s2 += __shfl_xor(s2, 8);
        float mu = s * (1.f / 128.f);
        float var = s2 * (1.f / 128.f) - mu * mu;
        float rstd = rsqrtf(var + EPSV);
        ushort4 o0, o1;
        o0.x = f2b((x[0] - mu) * rstd * lng[j * 8]     + lnb[j * 8]);
        o0.y = f2b((x[1] - mu) * rstd * lng[j * 8 + 1] + lnb[j * 8 + 1]);
        o0.z = f2b((x[2] - mu) * rstd * lng[j * 8 + 2] + lnb[j * 8 + 2]);
        o0.w = f2b((x[3] - mu) * rstd * lng[j * 8 + 3] + lnb[j * 8 + 3]);
        o1.x = f2b((x[4] - mu) * rstd * lng[j * 8 + 4] + lnb[j * 8 + 4]);
        o1.y = f2b((x[5] - mu) * rstd * lng[j * 8 + 5] + lnb[j * 8 + 5]);
        o1.z = f2b((x[6] - mu) * rstd * lng[j * 8 + 6] + lnb[j * 8 + 6]);
        o1.w = f2b((x[7] - mu) * rstd * lng[j * 8 + 7] + lnb[j * 8 + 7]);
        *(ushort4*)(hfin + (size_t)gnode * 128 + j * 8)     = o0;
        *(ushort4*)(hfin + (size_t)gnode * 128 + j * 8 + 4) = o1;
    }
}

// ---------------- classifier stats (F=64) ----------------
__global__ __launch_bounds__(256) void stats64_kernel(const float* __restrict__ z,
                                                      float* __restrict__ sums, int N) {
    __shared__ float ls[4][64], lsq[4][64];
    int f = threadIdx.x & 63, rg = threadIdx.x >> 6;
    int r0 = blockIdx.x * 64 + rg * 16;
    int r1 = r0 + 16; if (r1 > N) r1 = N;
    float s = 0.f, s2 = 0.f;
    for (int r = r0; r < r1; ++r) {
        float v = z[(size_t)r * 64 + f];
        s += v; s2 += v * v;
    }
    ls[rg][f] = s; lsq[rg][f] = s2;
    __syncthreads();
    int t = threadIdx.x;
    if (t < 64) atomicAdd(&sums[t], ls[0][t] + ls[1][t] + ls[2][t] + ls[3][t]);
    else if (t < 128) { int c = t - 64; atomicAdd(&sums[64 + c], lsq[0][c] + lsq[1][c] + lsq[2][c] + lsq[3][c]); }
}

// ---------------- final: BN(inline finalize)+ReLU+Linear(64,10)+log_softmax --
__global__ __launch_bounds__(256) void final_kernel(const float* __restrict__ z,
                                                    const float* __restrict__ sums,
                                                    const float* __restrict__ g,
                                                    const float* __restrict__ be,
                                                    const float* __restrict__ W2,
                                                    const float* __restrict__ b2v,
                                                    float* __restrict__ out, int nN) {
    int node = blockIdx.x * 4 + (threadIdx.x >> 6);
    int lane = threadIdx.x & 63;
    float inv = 1.f / (float)nN;
    float mean = sums[lane] * inv;
    float var = sums[64 + lane] * inv - mean * mean;
    float sc = g[lane] * rsqrtf(var + EPSV);
    float sh = be[lane] - mean * sc;
    float v = 0.f;
    if (node < nN) v = fmaxf(z[(size_t)node * 64 + lane] * sc + sh, 0.f);
    float p[10];
    const float* wrow = W2 + lane * 10;
#pragma unroll
    for (int c = 0; c < 10; ++c) p[c] = v * wrow[c];
#pragma unroll
    for (int off = 32; off >= 1; off >>= 1) {
#pragma unroll
        for (int c = 0; c < 10; ++c) p[c] += __shfl_xor(p[c], off);
    }
    if (node >= nN) return;
    float l[10], mx = -1e30f;
#pragma unroll
    for (int c = 0; c < 10; ++c) { l[c] = p[c] + b2v[c]; mx = fmaxf(mx, l[c]); }
    float se = 0.f;
#pragma unroll
    for (int c = 0; c < 10; ++c) se += expf(l[c] - mx);
    float lse = mx + logf(se);
    if (lane < 10) out[(size_t)node * 10 + lane] = l[lane] - lse;
}

// ---------------------------------------------------------------------------
static inline int cdiv(long a, long b) { return (int)((a + b - 1) / b); }

extern "C" void kernel_launch(void* const* d_in, const int* in_sizes, int n_in,
                              void* d_out, int out_size, void* d_ws, size_t ws_size,
                              hipStream_t stream) {
    const float* node_feat = (const float*)d_in[0];
    const int*   nedge     = (const int*)d_in[1];
    const float* comm_feat = (const float*)d_in[2];
    const int*   cedge     = (const int*)d_in[3];
    const int*   n2c       = (const int*)d_in[4];
    const float* node_W    = (const float*)d_in[5];
    const float* node_b    = (const float*)d_in[6];
    const float* node_g    = (const float*)d_in[7];
    const float* node_beta = (const float*)d_in[8];
    const float* comm_W    = (const float*)d_in[9];
    const float* comm_b    = (const float*)d_in[10];
    const float* comm_g    = (const float*)d_in[11];
    const float* comm_beta = (const float*)d_in[12];
    const float* attn_in_w = (const float*)d_in[13];
    const float* attn_in_b = (const float*)d_in[14];
    const float* attn_out_w= (const float*)d_in[15];
    const float* attn_out_b= (const float*)d_in[16];
    const float* ln_g      = (const float*)d_in[17];
    const float* ln_b      = (const float*)d_in[18];
    const float* cls_W1    = (const float*)d_in[19];
    const float* cls_b1    = (const float*)d_in[20];
    const float* cls_bn_g  = (const float*)d_in[21];
    const float* cls_bn_b  = (const float*)d_in[22];
    const float* cls_W2    = (const float*)d_in[23];
    const float* cls_b2    = (const float*)d_in[24];

    const int nN = in_sizes[0] / 128;
    const int nE = in_sizes[1] / 2;
    const int nC = in_sizes[2] / 128;
    const int cE = in_sizes[3] / 2;
    const int padE_n = nE + 8 * nN;
    const int padE_c = cE + 8 * nC;

    char* ws = (char*)d_ws;
    size_t off = 0;
    auto alloc = [&](size_t bytes) -> char* {
        char* p = ws + off;
        off = (off + bytes + 255) & ~(size_t)255;
        return p;
    };
    // ---- contiguous zero region (single memset) ----
    size_t zero_begin = off;
    int*   cnt_n  = (int*)alloc((size_t)nN * 4);
    int*   cur_n  = (int*)alloc((size_t)nN * 4);
    int*   cnt_c  = (int*)alloc((size_t)nC * 4);
    int*   cur_c  = (int*)alloc((size_t)nC * 4);
    float* gsums  = (float*)alloc((size_t)6 * 256 * 4);
    float* csums  = (float*)alloc(128 * 4);
    int*   csrc_n = (int*)alloc((size_t)padE_n * 4);   // pad slots stay 0
    float* cw_n   = (float*)alloc((size_t)padE_n * 4); // pad slots stay 0.0
    int*   csrc_c = (int*)alloc((size_t)padE_c * 4);
    float* cw_c   = (float*)alloc((size_t)padE_c * 4);
    size_t zero_bytes = off - zero_begin;
    // ---- CSR aux ----
    int*   rs_n   = (int*)alloc((size_t)(nN + 1) * 4);
    int*   bsum_n = (int*)alloc(256 * 4);
    float* dinv_n = (float*)alloc((size_t)nN * 4);
    int*   rs_c   = (int*)alloc((size_t)(nC + 1) * 4);
    int*   bsum_c = (int*)alloc(256 * 4);
    float* dinv_c = (float*)alloc((size_t)nC * 4);
    // ---- activations / weights ----
    unsigned short* hb_n  = (unsigned short*)alloc((size_t)nN * 256);
    unsigned short* hb_c  = (unsigned short*)alloc((size_t)nC * 256);
    unsigned short* cfb   = (unsigned short*)alloc((size_t)nC * 256);
    unsigned short* m_cb  = (unsigned short*)alloc((size_t)nC * 256);
    float*          agg_c = (float*)alloc((size_t)nC * 512);
    unsigned short* WtN  = (unsigned short*)alloc((size_t)3 * 16384 * 2);
    unsigned short* WtC  = (unsigned short*)alloc((size_t)3 * 16384 * 2);
    unsigned short* W1t  = (unsigned short*)alloc((size_t)64 * 128 * 2);
    unsigned short* WinB = (unsigned short*)alloc((size_t)384 * 128 * 2);
    unsigned short* WoutB= (unsigned short*)alloc((size_t)128 * 128 * 2);
    unsigned short* m_nb = (unsigned short*)alloc((size_t)nN * 256);
    float*          agg_n= (float*)alloc((size_t)nN * 512);
    // aliases (disjoint liveness)
    unsigned short* nfb  = (unsigned short*)agg_n;
    unsigned short* hfin = m_nb;
    float*          z    = agg_n;

    hipMemsetAsync(ws + zero_begin, 0, zero_bytes, stream);

    // ---- prep ----
    long prepN = 49152L * 3 + 8192 + 16384 + (long)nC * 128 + (long)nN * 128;
    prep_kernel<<<cdiv(prepN, 256), 256, 0, stream>>>(
        node_W, comm_W, cls_W1, attn_in_w, attn_out_w, comm_feat, node_feat,
        WtN, WtC, W1t, WinB, WoutB, cfb, nfb, nC * 128, nN * 128);

    // ---- CSR build (rows padded to x8) ----
    count_dual<<<cdiv((long)nE + cE, 256), 256, 0, stream>>>(nedge + nE, cnt_n, nE, cedge + cE, cnt_c, cE);
    dinv_dual<<<cdiv((long)nN + nC, 256), 256, 0, stream>>>(cnt_n, dinv_n, nN, cnt_c, dinv_c, nC);
    int nbN = cdiv(nN, 1024), nbC = cdiv(nC, 1024);
    scan_block_dual<<<nbN + nbC, 1024, 0, stream>>>(cnt_n, rs_n, bsum_n, nN, nbN, cnt_c, rs_c, bsum_c, nC);
    scan_sums_dual<<<1, 64, 0, stream>>>(bsum_n, nbN, bsum_c, nbC);
    scan_add_dual<<<cdiv((long)nN + nC, 256), 256, 0, stream>>>(rs_n, bsum_n, nN, rs_c, bsum_c, nC);
    fill_dual<<<cdiv((long)nE + cE, 256), 256, 0, stream>>>(
        nedge, nedge + nE, dinv_n, rs_n, cur_n, csrc_n, cw_n, nE,
        cedge, cedge + cE, dinv_c, rs_c, cur_c, csrc_c, cw_c, cE);

    // ---- GCN layers ----
    int gemmA = cdiv(nN, 128), gemmB = cdiv(nC, 128);
    int gatA = cdiv(nN, 4), gatB = cdiv(nC, 4);
    int appA = cdiv((long)nN * 128, 1024), appB = cdiv((long)nC * 128, 1024);
    for (int i = 0; i < 3; ++i) {
        const unsigned short* A0 = i == 0 ? nfb : hb_n;
        const unsigned short* A1 = i == 0 ? cfb : hb_c;
        float* s0 = gsums + (size_t)(i * 2 + 0) * 256;
        float* s1 = gsums + (size_t)(i * 2 + 1) * 256;
        gemm_dual<<<gemmA + gemmB, 256, 0, stream>>>(
            A0, WtN + i * 16384, m_nb, nN, gemmA,
            A1, WtC + i * 16384, m_cb, nC);
        gather_dual<<<gatA + gatB, 256, 0, stream>>>(
            m_nb, rs_n, cnt_n, csrc_n, cw_n, dinv_n, node_b + i * 128, agg_n, nN, gatA,
            m_cb, rs_c, cnt_c, csrc_c, cw_c, dinv_c, comm_b + i * 128, agg_c, nC);
        stats_dual<<<256 + 4, 256, 0, stream>>>(agg_n, s0, nN, 256, agg_c, s1, nC);
        apply_dual<<<appA + appB, 256, 0, stream>>>(
            agg_n, s0, node_g + i * 128, node_beta + i * 128, hb_n, nN, appA, i > 0 ? 1 : 0,
            agg_c, s1, comm_g + i * 128, comm_beta + i * 128, hb_c, nC);
    }

    // ---- fused MHA + mean + residual + LN ----
    mha_fused_kernel<<<cdiv(nN, 16), 256, 0, stream>>>(
        hb_n, hb_c, n2c, WinB, attn_in_b, WoutB, attn_out_b, ln_g, ln_b, hfin, nN, nC);

    // ---- classifier ----
    int waves1 = (nN + 15) / 16;
    gemm_kernel<<<cdiv((long)waves1 * 64, 256), 256, 0, stream>>>(
        hfin, W1t, cls_b1, z, nN, 64);
    stats64_kernel<<<cdiv(nN, 64), 256, 0, stream>>>(z, csums, nN);
    final_kernel<<<cdiv(nN, 4), 256, 0, stream>>>(z, csums, cls_bn_g, cls_bn_b,
                                                  cls_W2, cls_b2, (float*)d_out, nN);
}